// Round 2
// baseline (6849.283 us; speedup 1.0000x reference)
//
#include <hip/hip_runtime.h>

#define DI __device__ __forceinline__

typedef unsigned short u16;
typedef __bf16 bf16v __attribute__((ext_vector_type(8)));   // 8 bf16 = 4 VGPRs (MFMA A/B frag)
typedef float f32x4 __attribute__((ext_vector_type(4)));     // MFMA C/D frag

constexpr int B_ = 256, T_ = 2048, U_ = 32, Yd_ = 32, H_ = 128, Z_ = 64;
constexpr int BU = B_ * U_;        // 8192
constexpr int TC = 256;            // time-chunk length
constexpr int NCH = T_ / TC;       // 8 chunks
constexpr int RC = TC * B_;        // rows per chunk = 65536

// ---- bf16 weight pool offsets (elements) ----
constexpr size_t O_PU_W1 = 0;        // [128][32]
constexpr size_t O_PU_W2 = 4096;     // [128][128]
constexpr size_t O_DY_W1 = 20480;    // [128][256]
constexpr size_t O_DY_W2 = 53248;    // [128][128]
constexpr size_t O_XM_W  = 69632;    // [64][128]
constexpr size_t O_XLV_W = 77824;    // [64][128]
constexpr size_t O_PX_W1 = 86016;    // [128][128]
constexpr size_t O_PX_W2 = 102400;   // [128][128]
constexpr size_t O_ME_W1 = 118784;   // [128][128]
constexpr size_t O_ME_W2 = 135168;   // [32][128]
constexpr size_t O_WIH   = 139264;   // [2][384][128]
constexpr size_t O_WHH   = 237568;   // [2][384][128]

// ---- ws byte offsets (total ~42 MiB) ----
constexpr size_t WS_WB   = 0;                                // 672 KiB used
constexpr size_t WS_HST  = 0x100000;                         // h state [2][B][H] f32 (256 KiB)
constexpr size_t WS_PART = 0x140000;                         // 1024 f32 partials
constexpr size_t WS_UT   = 0x180000;                         // u^T chunk [TC][B*32] bf16 (4 MiB)
constexpr size_t WS_YT   = WS_UT + (size_t)RC * 32 * 2;      // y^T chunk (4 MiB)
constexpr size_t WS_PHIU = WS_YT + (size_t)RC * 32 * 2;      // phi_u chunk [RC][128] bf16 (16 MiB)
constexpr size_t WS_H1   = WS_PHIU + (size_t)RC * H_ * 2;    // h1(pre-update) chunk (16 MiB)

DI u16 f2b(float x) {
  union { float f; unsigned u; } v; v.f = x;
  unsigned r = v.u + 0x7fffu + ((v.u >> 16) & 1u);   // RNE
  return (u16)(r >> 16);
}
DI float b2f(u16 h) { union { unsigned u; float f; } v; v.u = ((unsigned)h) << 16; return v.f; }
DI float sigm(float x) { return 1.f / (1.f + __expf(-x)); }
DI float tanh_(float x) {
  float ax = fabsf(x); float e = __expf(-2.f * ax);
  float t = (1.f - e) / (1.f + e);
  return x < 0.f ? -t : t;
}
DI f32x4 MFMA(bf16v a, bf16v b, f32x4 c) {
  return __builtin_amdgcn_mfma_f32_16x16x32_bf16(a, b, c, 0, 0, 0);
}
DI bf16v ldb(const u16* p) { return *reinterpret_cast<const bf16v*>(p); }

// ============ kernel 1: convert weights f32 -> bf16 pool, init h state ============
__global__ void k_convert_weights(
    const float* pu_w1, const float* pu_w2, const float* dy_w1, const float* dy_w2,
    const float* xm_w, const float* xlv_w, const float* px_w1, const float* px_w2,
    const float* me_w1, const float* me_w2, const float* gih, const float* ghh,
    const float* h0, u16* wb, float* hst) {
  int i0 = blockIdx.x * blockDim.x + threadIdx.x;
  int st = gridDim.x * blockDim.x;
#define CVT(src, off, n) for (int i = i0; i < (n); i += st) wb[(off) + i] = f2b(src[i]);
  CVT(pu_w1, O_PU_W1, 4096)  CVT(pu_w2, O_PU_W2, 16384)
  CVT(dy_w1, O_DY_W1, 32768) CVT(dy_w2, O_DY_W2, 16384)
  CVT(xm_w,  O_XM_W,  8192)  CVT(xlv_w, O_XLV_W, 8192)
  CVT(px_w1, O_PX_W1, 16384) CVT(px_w2, O_PX_W2, 16384)
  CVT(me_w1, O_ME_W1, 16384) CVT(me_w2, O_ME_W2, 4096)
  CVT(gih,   O_WIH,   98304) CVT(ghh,   O_WHH,   98304)
#undef CVT
  for (int i = i0; i < 2 * B_ * H_; i += st) hst[i] = h0[i];
}

// ============ kernel 2: transpose u,y slice: [BU][T] f32 -> [TC][BU] bf16 ============
__global__ void k_transpose(const float* __restrict__ u, const float* __restrict__ y,
                            u16* __restrict__ uT, u16* __restrict__ yT, int t0) {
  const float* src = blockIdx.z ? y : u;
  u16* dst = blockIdx.z ? yT : uT;
  __shared__ float tile[32][33];
  const int tx = threadIdx.x, ty = threadIdx.y;      // 32 x 8
  const int c0 = blockIdx.x * 32;                    // t (chunk-local)
  const int r0 = blockIdx.y * 32;                    // b*32+chan
#pragma unroll
  for (int i = 0; i < 4; ++i)
    tile[ty + i * 8][tx] = src[(size_t)(r0 + ty + i * 8) * T_ + t0 + c0 + tx];
  __syncthreads();
#pragma unroll
  for (int i = 0; i < 4; ++i)
    dst[(size_t)(c0 + ty + i * 8) * BU + r0 + tx] = f2b(tile[tx][ty + i * 8]);
}

// ============ kernel 3: phi_u for one chunk (RC rows) ============
__global__ __launch_bounds__(256) void k_phi_u(
    const u16* __restrict__ uT, const u16* __restrict__ wb,
    const float* __restrict__ pu_b1, const float* __restrict__ pu_b2,
    u16* __restrict__ phiu) {
  __shared__ __align__(16) u16 hid[4][32 * 136];
  const int lane = threadIdx.x & 63, w = threadIdx.x >> 6;
  const int ln = lane & 15, lq = lane >> 4;
  const int r0 = (blockIdx.x * 4 + w) * 32;
  u16* hb = hid[w];

  // layer 1: K=32, out 128, relu
  bf16v a0 = ldb(uT + (size_t)(r0 + ln) * 32 + lq * 8);
  bf16v a1 = ldb(uT + (size_t)(r0 + 16 + ln) * 32 + lq * 8);
  const u16* w1 = wb + O_PU_W1;
#pragma unroll
  for (int nt = 0; nt < 8; ++nt) {
    f32x4 c0 = {0.f, 0.f, 0.f, 0.f}, c1 = {0.f, 0.f, 0.f, 0.f};
    bf16v b = ldb(w1 + (nt * 16 + ln) * 32 + lq * 8);
    c0 = MFMA(a0, b, c0); c1 = MFMA(a1, b, c1);
    float bv = pu_b1[nt * 16 + ln];
#pragma unroll
    for (int j = 0; j < 4; ++j) {
      hb[(lq * 4 + j) * 136 + nt * 16 + ln]        = f2b(fmaxf(c0[j] + bv, 0.f));
      hb[(16 + lq * 4 + j) * 136 + nt * 16 + ln]   = f2b(fmaxf(c1[j] + bv, 0.f));
    }
  }
  // layer 2: K=128, out 128 -> global
  bf16v a[2][4];
#pragma unroll
  for (int mt = 0; mt < 2; ++mt)
#pragma unroll
    for (int kt = 0; kt < 4; ++kt)
      a[mt][kt] = ldb(hb + (mt * 16 + ln) * 136 + kt * 32 + lq * 8);
  const u16* w2 = wb + O_PU_W2;
#pragma unroll
  for (int nt = 0; nt < 8; ++nt) {
    f32x4 c0 = {0.f, 0.f, 0.f, 0.f}, c1 = {0.f, 0.f, 0.f, 0.f};
#pragma unroll
    for (int kt = 0; kt < 4; ++kt) {
      bf16v b = ldb(w2 + (nt * 16 + ln) * 128 + kt * 32 + lq * 8);
      c0 = MFMA(a[0][kt], b, c0); c1 = MFMA(a[1][kt], b, c1);
    }
    float bv = pu_b2[nt * 16 + ln];
#pragma unroll
    for (int mt = 0; mt < 2; ++mt)
#pragma unroll
      for (int j = 0; j < 4; ++j) {
        float v = (mt ? c1[j] : c0[j]) + bv;
        phiu[(size_t)(r0 + mt * 16 + lq * 4 + j) * H_ + nt * 16 + ln] = f2b(v);
      }
  }
}

// ============ kernel 4: sequential 2-layer GRU over one chunk, 16 WGs ============
__global__ __launch_bounds__(512) void k_gru_seq(
    const u16* __restrict__ phiu, const u16* __restrict__ wb,
    float* __restrict__ hst, u16* __restrict__ h1old) {
  __shared__ __align__(16) u16 H0[2][16 * 136];
  __shared__ __align__(16) u16 H1[2][16 * 136];
  const int lane = threadIdx.x & 63, w = threadIdx.x >> 6;   // 8 waves
  const int ln = lane & 15, lq = lane >> 4;
  const int f0 = w * 16;                                      // feature slice
  const int b0 = blockIdx.x * 16;
  const u16* wi0 = wb + O_WIH;
  const u16* wh0 = wb + O_WHH;
  const u16* wi1 = wi0 + 49152;
  const u16* wh1 = wh0 + 49152;

  float h0s[4], h1s[4];
#pragma unroll
  for (int j = 0; j < 4; ++j) {
    int m = lq * 4 + j;
    h0s[j] = hst[(size_t)(0 * B_ + b0 + m) * H_ + f0 + ln];
    h1s[j] = hst[(size_t)(1 * B_ + b0 + m) * H_ + f0 + ln];
    H0[0][m * 136 + f0 + ln] = f2b(h0s[j]);
    H1[0][m * 136 + f0 + ln] = f2b(h1s[j]);
    h1old[(size_t)(b0 + m) * H_ + f0 + ln] = f2b(h1s[j]);    // chunk-local t = 0 slot
  }
  __syncthreads();

  // prefetch phi_u A-frags for t=0
  bf16v aPn[4];
#pragma unroll
  for (int kt = 0; kt < 4; ++kt)
    aPn[kt] = ldb(phiu + ((size_t)0 * B_ + b0 + ln) * H_ + kt * 32 + lq * 8);

  for (int t = 0; t < TC; ++t) {
    const int cur = t & 1, nxt = cur ^ 1;
    bf16v aP[4];
#pragma unroll
    for (int kt = 0; kt < 4; ++kt) aP[kt] = aPn[kt];
    if (t + 1 < TC) {                                         // prefetch next step
#pragma unroll
      for (int kt = 0; kt < 4; ++kt)
        aPn[kt] = ldb(phiu + ((size_t)(t + 1) * B_ + b0 + ln) * H_ + kt * 32 + lq * 8);
    }
    // ---- layer 0: gi0 = phi_u @ Wih0^T ; gh0 = h0 @ Whh0^T ----
    bf16v aH[4];
#pragma unroll
    for (int kt = 0; kt < 4; ++kt)
      aH[kt] = ldb(&H0[cur][ln * 136 + kt * 32 + lq * 8]);
    f32x4 cIR = {0,0,0,0}, cIZ = {0,0,0,0}, cIN = {0,0,0,0};
    f32x4 cHR = {0,0,0,0}, cHZ = {0,0,0,0}, cHN = {0,0,0,0};
#pragma unroll
    for (int kt = 0; kt < 4; ++kt) {
      int kb = kt * 32 + lq * 8;
      bf16v bIR = ldb(wi0 + (f0 + ln) * H_ + kb);
      bf16v bIZ = ldb(wi0 + (128 + f0 + ln) * H_ + kb);
      bf16v bIN = ldb(wi0 + (256 + f0 + ln) * H_ + kb);
      bf16v bHR = ldb(wh0 + (f0 + ln) * H_ + kb);
      bf16v bHZ = ldb(wh0 + (128 + f0 + ln) * H_ + kb);
      bf16v bHN = ldb(wh0 + (256 + f0 + ln) * H_ + kb);
      cIR = MFMA(aP[kt], bIR, cIR); cIZ = MFMA(aP[kt], bIZ, cIZ); cIN = MFMA(aP[kt], bIN, cIN);
      cHR = MFMA(aH[kt], bHR, cHR); cHZ = MFMA(aH[kt], bHZ, cHZ); cHN = MFMA(aH[kt], bHN, cHN);
    }
#pragma unroll
    for (int j = 0; j < 4; ++j) {
      float r = sigm(cIR[j] + cHR[j]);
      float z = sigm(cIZ[j] + cHZ[j]);
      float n = tanh_(cIN[j] + r * cHN[j]);
      float h = n + z * (h0s[j] - n);
      h0s[j] = h;
      H0[nxt][(lq * 4 + j) * 136 + f0 + ln] = f2b(h);
    }
    __syncthreads();
    // ---- layer 1: gi1 = h0' @ Wih1^T ; gh1 = h1 @ Whh1^T ----
    bf16v aI[4], aH1[4];
#pragma unroll
    for (int kt = 0; kt < 4; ++kt) {
      aI[kt]  = ldb(&H0[nxt][ln * 136 + kt * 32 + lq * 8]);
      aH1[kt] = ldb(&H1[cur][ln * 136 + kt * 32 + lq * 8]);
    }
    f32x4 dIR = {0,0,0,0}, dIZ = {0,0,0,0}, dIN = {0,0,0,0};
    f32x4 dHR = {0,0,0,0}, dHZ = {0,0,0,0}, dHN = {0,0,0,0};
#pragma unroll
    for (int kt = 0; kt < 4; ++kt) {
      int kb = kt * 32 + lq * 8;
      bf16v bIR = ldb(wi1 + (f0 + ln) * H_ + kb);
      bf16v bIZ = ldb(wi1 + (128 + f0 + ln) * H_ + kb);
      bf16v bIN = ldb(wi1 + (256 + f0 + ln) * H_ + kb);
      bf16v bHR = ldb(wh1 + (f0 + ln) * H_ + kb);
      bf16v bHZ = ldb(wh1 + (128 + f0 + ln) * H_ + kb);
      bf16v bHN = ldb(wh1 + (256 + f0 + ln) * H_ + kb);
      dIR = MFMA(aI[kt], bIR, dIR); dIZ = MFMA(aI[kt], bIZ, dIZ); dIN = MFMA(aI[kt], bIN, dIN);
      dHR = MFMA(aH1[kt], bHR, dHR); dHZ = MFMA(aH1[kt], bHZ, dHZ); dHN = MFMA(aH1[kt], bHN, dHN);
    }
#pragma unroll
    for (int j = 0; j < 4; ++j) {
      float r = sigm(dIR[j] + dHR[j]);
      float z = sigm(dIZ[j] + dHZ[j]);
      float n = tanh_(dIN[j] + r * dHN[j]);
      float h = n + z * (h1s[j] - n);
      h1s[j] = h;
      H1[nxt][(lq * 4 + j) * 136 + f0 + ln] = f2b(h);
      if (t + 1 < TC)
        h1old[((size_t)(t + 1) * B_ + b0 + lq * 4 + j) * H_ + f0 + ln] = f2b(h);
    }
    __syncthreads();
  }

  // persist h state for next chunk
#pragma unroll
  for (int j = 0; j < 4; ++j) {
    int m = lq * 4 + j;
    hst[(size_t)(0 * B_ + b0 + m) * H_ + f0 + ln] = h0s[j];
    hst[(size_t)(1 * B_ + b0 + m) * H_ + f0 + ln] = h1s[j];
  }
}

// ============ kernel 5: post-chain + loss partials (one chunk) ============
DI void layer128(const u16* __restrict__ W, const float* __restrict__ bias,
                 const u16* A, u16* Dst, int dstOff, int nTiles, bool relu,
                 int ln, int lq) {
  bf16v a[2][4];
#pragma unroll
  for (int mt = 0; mt < 2; ++mt)
#pragma unroll
    for (int kt = 0; kt < 4; ++kt)
      a[mt][kt] = ldb(A + (mt * 16 + ln) * 136 + kt * 32 + lq * 8);
  for (int nt = 0; nt < nTiles; ++nt) {
    f32x4 c0 = {0,0,0,0}, c1 = {0,0,0,0};
#pragma unroll
    for (int kt = 0; kt < 4; ++kt) {
      bf16v b = ldb(W + (nt * 16 + ln) * 128 + kt * 32 + lq * 8);
      c0 = MFMA(a[0][kt], b, c0); c1 = MFMA(a[1][kt], b, c1);
    }
    float bv = bias[nt * 16 + ln];
#pragma unroll
    for (int mt = 0; mt < 2; ++mt)
#pragma unroll
      for (int j = 0; j < 4; ++j) {
        float v = (mt ? c1[j] : c0[j]) + bv;
        if (relu) v = fmaxf(v, 0.f);
        Dst[(mt * 16 + lq * 4 + j) * 136 + dstOff + nt * 16 + ln] = f2b(v);
      }
  }
}

__global__ __launch_bounds__(128) void k_post(
    const u16* __restrict__ phiu, const u16* __restrict__ h1old,
    const u16* __restrict__ yT, const u16* __restrict__ wb,
    const float* __restrict__ dy_b1, const float* __restrict__ dy_b2,
    const float* __restrict__ xm_b, const float* __restrict__ xlv_b,
    const float* __restrict__ px_b1, const float* __restrict__ px_b2,
    const float* __restrict__ me_b1, const float* __restrict__ me_b2,
    float* __restrict__ partials, int first) {
  __shared__ __align__(16) u16 buf[2][2][32 * 136];
  __shared__ float wsum[2];
  const int lane = threadIdx.x & 63, w = threadIdx.x >> 6;   // 2 waves
  const int ln = lane & 15, lq = lane >> 4;
  const int r0 = (blockIdx.x * 2 + w) * 32;
  u16* X = buf[w][0];
  u16* Yb = buf[w][1];

  // step 1: dy hidden = relu([phi_u||h1old] @ dy_w1^T + b1), K=256 -> X
  {
    bf16v a[2][8];
#pragma unroll
    for (int mt = 0; mt < 2; ++mt)
#pragma unroll
      for (int kt = 0; kt < 8; ++kt) {
        size_t row = (size_t)(r0 + mt * 16 + ln);
        a[mt][kt] = (kt < 4) ? ldb(phiu + row * H_ + kt * 32 + lq * 8)
                             : ldb(h1old + row * H_ + (kt - 4) * 32 + lq * 8);
      }
    const u16* W = wb + O_DY_W1;
    for (int nt = 0; nt < 8; ++nt) {
      f32x4 c0 = {0,0,0,0}, c1 = {0,0,0,0};
#pragma unroll
      for (int kt = 0; kt < 8; ++kt) {
        bf16v b = ldb(W + (nt * 16 + ln) * 256 + kt * 32 + lq * 8);
        c0 = MFMA(a[0][kt], b, c0); c1 = MFMA(a[1][kt], b, c1);
      }
      float bv = dy_b1[nt * 16 + ln];
#pragma unroll
      for (int mt = 0; mt < 2; ++mt)
#pragma unroll
        for (int j = 0; j < 4; ++j) {
          float v = (mt ? c1[j] : c0[j]) + bv;
          X[(mt * 16 + lq * 4 + j) * 136 + nt * 16 + ln] = f2b(fmaxf(v, 0.f));
        }
    }
  }
  layer128(wb + O_DY_W2, dy_b2, X, Yb, 0, 8, false, ln, lq);   // dphi
  layer128(wb + O_XM_W,  xm_b,  Yb, X, 0, 4, false, ln, lq);   // x_mean   -> X[:,0:64]
  layer128(wb + O_XLV_W, xlv_b, Yb, X, 64, 4, false, ln, lq);  // x_logvar -> X[:,64:128]
  layer128(wb + O_PX_W1, px_b1, X, Yb, 0, 8, true,  ln, lq);   // px hidden
  layer128(wb + O_PX_W2, px_b2, Yb, X, 0, 8, false, ln, lq);   // phi_x
  layer128(wb + O_ME_W1, me_b1, X, Yb, 0, 8, true,  ln, lq);   // me hidden

  // final: y_hat = Yb @ me_w2^T + b2 ; loss += (y_hat - y)^2
  float lsum = 0.f;
  {
    bf16v a[2][4];
#pragma unroll
    for (int mt = 0; mt < 2; ++mt)
#pragma unroll
      for (int kt = 0; kt < 4; ++kt)
        a[mt][kt] = ldb(Yb + (mt * 16 + ln) * 136 + kt * 32 + lq * 8);
    const u16* W = wb + O_ME_W2;
#pragma unroll
    for (int nt = 0; nt < 2; ++nt) {
      f32x4 c0 = {0,0,0,0}, c1 = {0,0,0,0};
#pragma unroll
      for (int kt = 0; kt < 4; ++kt) {
        bf16v b = ldb(W + (nt * 16 + ln) * 128 + kt * 32 + lq * 8);
        c0 = MFMA(a[0][kt], b, c0); c1 = MFMA(a[1][kt], b, c1);
      }
      float bv = me_b2[nt * 16 + ln];
#pragma unroll
      for (int mt = 0; mt < 2; ++mt)
#pragma unroll
        for (int j = 0; j < 4; ++j) {
          int m = mt * 16 + lq * 4 + j;
          float v = (mt ? c1[j] : c0[j]) + bv;
          float yv = b2f(yT[(size_t)(r0 + m) * 32 + nt * 16 + ln]);
          float d = v - yv;
          lsum += d * d;
        }
    }
  }
#pragma unroll
  for (int o = 32; o; o >>= 1) lsum += __shfl_down(lsum, o);
  if (lane == 0) wsum[w] = lsum;
  __syncthreads();
  if (threadIdx.x == 0) {
    float v = wsum[0] + wsum[1];
    if (first) partials[blockIdx.x] = v;
    else       partials[blockIdx.x] += v;
  }
}

// ============ kernel 6: deterministic final reduction ============
__global__ void k_finalize(const float* __restrict__ partials, float* __restrict__ out) {
  __shared__ double s[256];
  double acc = 0.0;
  for (int i = threadIdx.x; i < 1024; i += 256) acc += (double)partials[i];
  s[threadIdx.x] = acc;
  __syncthreads();
  for (int o = 128; o; o >>= 1) {
    if (threadIdx.x < o) s[threadIdx.x] += s[threadIdx.x + o];
    __syncthreads();
  }
  if (threadIdx.x == 0) out[0] = (float)s[0];
}

extern "C" void kernel_launch(void* const* d_in, const int* in_sizes, int n_in,
                              void* d_out, int out_size, void* d_ws, size_t ws_size,
                              hipStream_t stream) {
  const float* u     = (const float*)d_in[0];
  const float* y     = (const float*)d_in[1];
  const float* h0    = (const float*)d_in[2];
  const float* pu_w1 = (const float*)d_in[3];
  const float* pu_b1 = (const float*)d_in[4];
  const float* pu_w2 = (const float*)d_in[5];
  const float* pu_b2 = (const float*)d_in[6];
  const float* dy_w1 = (const float*)d_in[7];
  const float* dy_b1 = (const float*)d_in[8];
  const float* dy_w2 = (const float*)d_in[9];
  const float* dy_b2 = (const float*)d_in[10];
  const float* xm_w  = (const float*)d_in[11];
  const float* xm_b  = (const float*)d_in[12];
  const float* xlv_w = (const float*)d_in[13];
  const float* xlv_b = (const float*)d_in[14];
  const float* px_w1 = (const float*)d_in[15];
  const float* px_b1 = (const float*)d_in[16];
  const float* px_w2 = (const float*)d_in[17];
  const float* px_b2 = (const float*)d_in[18];
  const float* me_w1 = (const float*)d_in[19];
  const float* me_b1 = (const float*)d_in[20];
  const float* me_w2 = (const float*)d_in[21];
  const float* me_b2 = (const float*)d_in[22];
  const float* gih   = (const float*)d_in[23];
  const float* ghh   = (const float*)d_in[24];

  char* ws = (char*)d_ws;
  u16* wb    = (u16*)(ws + WS_WB);
  float* hst = (float*)(ws + WS_HST);
  float* prt = (float*)(ws + WS_PART);
  u16* uT    = (u16*)(ws + WS_UT);
  u16* yT    = (u16*)(ws + WS_YT);
  u16* phiu  = (u16*)(ws + WS_PHIU);
  u16* h1o   = (u16*)(ws + WS_H1);
  float* out = (float*)d_out;

  k_convert_weights<<<256, 256, 0, stream>>>(pu_w1, pu_w2, dy_w1, dy_w2, xm_w, xlv_w,
                                             px_w1, px_w2, me_w1, me_w2, gih, ghh,
                                             h0, wb, hst);
  for (int c = 0; c < NCH; ++c) {
    k_transpose<<<dim3(TC / 32, 256, 2), dim3(32, 8), 0, stream>>>(u, y, uT, yT, c * TC);
    k_phi_u<<<RC / 128, 256, 0, stream>>>(uT, wb, pu_b1, pu_b2, phiu);
    k_gru_seq<<<16, 512, 0, stream>>>(phiu, wb, hst, h1o);
    k_post<<<RC / 64, 128, 0, stream>>>(phiu, h1o, yT, wb, dy_b1, dy_b2, xm_b, xlv_b,
                                        px_b1, px_b2, me_b1, me_b2, prt, c == 0 ? 1 : 0);
  }
  k_finalize<<<1, 256, 0, stream>>>(prt, out);
}

// Round 3
// 4650.377 us; speedup vs baseline: 1.4728x; 1.4728x over previous
//
#include <hip/hip_runtime.h>

#define DI __device__ __forceinline__

typedef unsigned short u16;
typedef __bf16 bf16v __attribute__((ext_vector_type(8)));   // 8 bf16 = 4 VGPRs (MFMA A/B frag)
typedef float f32x4 __attribute__((ext_vector_type(4)));     // MFMA C/D frag

constexpr int B_ = 256, T_ = 2048, U_ = 32, Yd_ = 32, H_ = 128, Z_ = 64;
constexpr int BU = B_ * U_;        // 8192
constexpr int TC = 256;            // time-chunk length
constexpr int NCH = T_ / TC;       // 8 chunks
constexpr int RC = TC * B_;        // rows per chunk = 65536

// ---- bf16 weight pool offsets (elements) ----
constexpr size_t O_PU_W1 = 0;        // [128][32]
constexpr size_t O_PU_W2 = 4096;     // [128][128]
constexpr size_t O_DY_W1 = 20480;    // [128][256]
constexpr size_t O_DY_W2 = 53248;    // [128][128]
constexpr size_t O_XM_W  = 69632;    // [64][128]
constexpr size_t O_XLV_W = 77824;    // [64][128]
constexpr size_t O_PX_W1 = 86016;    // [128][128]
constexpr size_t O_PX_W2 = 102400;   // [128][128]
constexpr size_t O_ME_W1 = 118784;   // [128][128]
constexpr size_t O_ME_W2 = 135168;   // [32][128]
constexpr size_t O_WIH   = 139264;   // [2][384][128]
constexpr size_t O_WHH   = 237568;   // [2][384][128]

// ---- ws byte offsets (total ~42 MiB) ----
constexpr size_t WS_WB   = 0;                                // 672 KiB used
constexpr size_t WS_HST  = 0x100000;                         // h state [2][B][H] f32 (256 KiB)
constexpr size_t WS_PART = 0x140000;                         // 1024 f32 partials
constexpr size_t WS_UT   = 0x180000;                         // u^T chunk [TC][B*32] bf16 (4 MiB)
constexpr size_t WS_YT   = WS_UT + (size_t)RC * 32 * 2;      // y^T chunk (4 MiB)
constexpr size_t WS_PHIU = WS_YT + (size_t)RC * 32 * 2;      // phi_u chunk [RC][128] bf16 (16 MiB)
constexpr size_t WS_H1   = WS_PHIU + (size_t)RC * H_ * 2;    // h1(pre-update) chunk (16 MiB)

DI u16 f2b(float x) {
  union { float f; unsigned u; } v; v.f = x;
  unsigned r = v.u + 0x7fffu + ((v.u >> 16) & 1u);   // RNE
  return (u16)(r >> 16);
}
DI float b2f(u16 h) { union { unsigned u; float f; } v; v.u = ((unsigned)h) << 16; return v.f; }
// select-free fast gates (exp2-based; rcp(inf)=0 handles saturation)
DI float sigm(float x) {
  return __builtin_amdgcn_rcpf(1.f + __builtin_amdgcn_exp2f(-1.44269504f * x));
}
DI float tanhg(float x) {
  return fmaf(2.f, __builtin_amdgcn_rcpf(1.f + __builtin_amdgcn_exp2f(-2.88539008f * x)), -1.f);
}
DI f32x4 MFMA(bf16v a, bf16v b, f32x4 c) {
  return __builtin_amdgcn_mfma_f32_16x16x32_bf16(a, b, c, 0, 0, 0);
}
DI bf16v ldb(const u16* p) { return *reinterpret_cast<const bf16v*>(p); }

// ============ kernel 1: convert weights f32 -> bf16 pool, init h state ============
__global__ void k_convert_weights(
    const float* pu_w1, const float* pu_w2, const float* dy_w1, const float* dy_w2,
    const float* xm_w, const float* xlv_w, const float* px_w1, const float* px_w2,
    const float* me_w1, const float* me_w2, const float* gih, const float* ghh,
    const float* h0, u16* wb, float* hst) {
  int i0 = blockIdx.x * blockDim.x + threadIdx.x;
  int st = gridDim.x * blockDim.x;
#define CVT(src, off, n) for (int i = i0; i < (n); i += st) wb[(off) + i] = f2b(src[i]);
  CVT(pu_w1, O_PU_W1, 4096)  CVT(pu_w2, O_PU_W2, 16384)
  CVT(dy_w1, O_DY_W1, 32768) CVT(dy_w2, O_DY_W2, 16384)
  CVT(xm_w,  O_XM_W,  8192)  CVT(xlv_w, O_XLV_W, 8192)
  CVT(px_w1, O_PX_W1, 16384) CVT(px_w2, O_PX_W2, 16384)
  CVT(me_w1, O_ME_W1, 16384) CVT(me_w2, O_ME_W2, 4096)
  CVT(gih,   O_WIH,   98304) CVT(ghh,   O_WHH,   98304)
#undef CVT
  for (int i = i0; i < 2 * B_ * H_; i += st) hst[i] = h0[i];
}

// ============ kernel 2: transpose u,y slice: [BU][T] f32 -> [TC][BU] bf16 ============
__global__ void k_transpose(const float* __restrict__ u, const float* __restrict__ y,
                            u16* __restrict__ uT, u16* __restrict__ yT, int t0) {
  const float* src = blockIdx.z ? y : u;
  u16* dst = blockIdx.z ? yT : uT;
  __shared__ float tile[32][33];
  const int tx = threadIdx.x, ty = threadIdx.y;      // 32 x 8
  const int c0 = blockIdx.x * 32;                    // t (chunk-local)
  const int r0 = blockIdx.y * 32;                    // b*32+chan
#pragma unroll
  for (int i = 0; i < 4; ++i)
    tile[ty + i * 8][tx] = src[(size_t)(r0 + ty + i * 8) * T_ + t0 + c0 + tx];
  __syncthreads();
#pragma unroll
  for (int i = 0; i < 4; ++i)
    dst[(size_t)(c0 + ty + i * 8) * BU + r0 + tx] = f2b(tile[tx][ty + i * 8]);
}

// ============ kernel 3: phi_u for one chunk (RC rows) ============
__global__ __launch_bounds__(256) void k_phi_u(
    const u16* __restrict__ uT, const u16* __restrict__ wb,
    const float* __restrict__ pu_b1, const float* __restrict__ pu_b2,
    u16* __restrict__ phiu) {
  __shared__ __align__(16) u16 hid[4][32 * 136];
  const int lane = threadIdx.x & 63, w = threadIdx.x >> 6;
  const int ln = lane & 15, lq = lane >> 4;
  const int r0 = (blockIdx.x * 4 + w) * 32;
  u16* hb = hid[w];

  // layer 1: K=32, out 128, relu
  bf16v a0 = ldb(uT + (size_t)(r0 + ln) * 32 + lq * 8);
  bf16v a1 = ldb(uT + (size_t)(r0 + 16 + ln) * 32 + lq * 8);
  const u16* w1 = wb + O_PU_W1;
#pragma unroll
  for (int nt = 0; nt < 8; ++nt) {
    f32x4 c0 = {0.f, 0.f, 0.f, 0.f}, c1 = {0.f, 0.f, 0.f, 0.f};
    bf16v b = ldb(w1 + (nt * 16 + ln) * 32 + lq * 8);
    c0 = MFMA(a0, b, c0); c1 = MFMA(a1, b, c1);
    float bv = pu_b1[nt * 16 + ln];
#pragma unroll
    for (int j = 0; j < 4; ++j) {
      hb[(lq * 4 + j) * 136 + nt * 16 + ln]        = f2b(fmaxf(c0[j] + bv, 0.f));
      hb[(16 + lq * 4 + j) * 136 + nt * 16 + ln]   = f2b(fmaxf(c1[j] + bv, 0.f));
    }
  }
  // layer 2: K=128, out 128 -> global
  bf16v a[2][4];
#pragma unroll
  for (int mt = 0; mt < 2; ++mt)
#pragma unroll
    for (int kt = 0; kt < 4; ++kt)
      a[mt][kt] = ldb(hb + (mt * 16 + ln) * 136 + kt * 32 + lq * 8);
  const u16* w2 = wb + O_PU_W2;
#pragma unroll
  for (int nt = 0; nt < 8; ++nt) {
    f32x4 c0 = {0.f, 0.f, 0.f, 0.f}, c1 = {0.f, 0.f, 0.f, 0.f};
#pragma unroll
    for (int kt = 0; kt < 4; ++kt) {
      bf16v b = ldb(w2 + (nt * 16 + ln) * 128 + kt * 32 + lq * 8);
      c0 = MFMA(a[0][kt], b, c0); c1 = MFMA(a[1][kt], b, c1);
    }
    float bv = pu_b2[nt * 16 + ln];
#pragma unroll
    for (int mt = 0; mt < 2; ++mt)
#pragma unroll
      for (int j = 0; j < 4; ++j) {
        float v = (mt ? c1[j] : c0[j]) + bv;
        phiu[(size_t)(r0 + mt * 16 + lq * 4 + j) * H_ + nt * 16 + ln] = f2b(v);
      }
  }
}

// ============ kernel 4: sequential 2-layer GRU over one chunk, 16 WGs ============
// Weights register/LDS-resident; ONE barrier per step; prefetch placed post-barrier.
__global__ __launch_bounds__(512) void k_gru_seq(
    const u16* __restrict__ phiu, const u16* __restrict__ wb,
    float* __restrict__ hst, u16* __restrict__ h1old) {
  __shared__ __align__(16) u16 H0[2][16 * 136];
  __shared__ __align__(16) u16 H1[2][16 * 136];
  __shared__ __align__(16) u16 WH1s[384 * 136];   // wh1 staged, padded rows (16B-aligned)
  const int lane = threadIdx.x & 63, w = threadIdx.x >> 6;   // 8 waves
  const int ln = lane & 15, lq = lane >> 4;
  const int f0 = w * 16;                                      // feature slice
  const int b0 = blockIdx.x * 16;
  const u16* wi0 = wb + O_WIH;
  const u16* wh0 = wb + O_WHH;
  const u16* wi1 = wi0 + 49152;
  const u16* wh1 = wh0 + 49152;

  // stage wh1 -> LDS (one-time)
#pragma unroll
  for (int p = 0; p < 12; ++p) {
    int r = p * 32 + (threadIdx.x >> 4);
    int c = (threadIdx.x & 15) * 8;
    *reinterpret_cast<bf16v*>(&WH1s[r * 136 + c]) = ldb(wh1 + r * 128 + c);
  }

  // preload remaining GRU weights into registers (loop-invariant)
  bf16v wI0[3][4], wH0[3][4], wI1[3][4];
#pragma unroll
  for (int g = 0; g < 3; ++g)
#pragma unroll
    for (int kt = 0; kt < 4; ++kt) {
      size_t row = (size_t)(g * 128 + f0 + ln);
      wI0[g][kt] = ldb(wi0 + row * H_ + kt * 32 + lq * 8);
      wH0[g][kt] = ldb(wh0 + row * H_ + kt * 32 + lq * 8);
      wI1[g][kt] = ldb(wi1 + row * H_ + kt * 32 + lq * 8);
    }

  float h0s[4], h1s[4];
#pragma unroll
  for (int j = 0; j < 4; ++j) {
    int m = lq * 4 + j;
    h0s[j] = hst[(size_t)(0 * B_ + b0 + m) * H_ + f0 + ln];
    h1s[j] = hst[(size_t)(1 * B_ + b0 + m) * H_ + f0 + ln];
    H0[0][m * 136 + f0 + ln] = f2b(h0s[j]);
    H1[0][m * 136 + f0 + ln] = f2b(h1s[j]);
    h1old[(size_t)(b0 + m) * H_ + f0 + ln] = f2b(h1s[j]);    // chunk-local t = 0 slot
  }

  // prefetch phi_u A-frags for t=0
  bf16v aP[4];
#pragma unroll
  for (int kt = 0; kt < 4; ++kt)
    aP[kt] = ldb(phiu + ((size_t)0 * B_ + b0 + ln) * H_ + kt * 32 + lq * 8);

  __syncthreads();

  for (int t = 0; t < TC; ++t) {
    const int cur = t & 1, nxt = cur ^ 1;
    // ---- layer 0: gi0 = phi_u @ Wih0^T ; gh0 = h0 @ Whh0^T ----
    bf16v aH[4];
#pragma unroll
    for (int kt = 0; kt < 4; ++kt)
      aH[kt] = ldb(&H0[cur][ln * 136 + kt * 32 + lq * 8]);
    f32x4 cIR = {0,0,0,0}, cIZ = {0,0,0,0}, cIN = {0,0,0,0};
    f32x4 cHR = {0,0,0,0}, cHZ = {0,0,0,0}, cHN = {0,0,0,0};
#pragma unroll
    for (int kt = 0; kt < 4; ++kt) {
      cIR = MFMA(aP[kt], wI0[0][kt], cIR);
      cIZ = MFMA(aP[kt], wI0[1][kt], cIZ);
      cIN = MFMA(aP[kt], wI0[2][kt], cIN);
      cHR = MFMA(aH[kt], wH0[0][kt], cHR);
      cHZ = MFMA(aH[kt], wH0[1][kt], cHZ);
      cHN = MFMA(aH[kt], wH0[2][kt], cHN);
    }
#pragma unroll
    for (int j = 0; j < 4; ++j) {
      float r = sigm(cIR[j] + cHR[j]);
      float z = sigm(cIZ[j] + cHZ[j]);
      float n = tanhg(fmaf(r, cHN[j], cIN[j]));
      float h = fmaf(z, h0s[j] - n, n);
      h0s[j] = h;
      H0[nxt][(lq * 4 + j) * 136 + f0 + ln] = f2b(h);
    }
    __syncthreads();   // the ONLY barrier per step

    // prefetch phi_u for t+1 AFTER the barrier: its vmcnt drain lands next step,
    // after consumption — latency hidden under L1 + gates + next L0.
    if (t + 1 < TC) {
#pragma unroll
      for (int kt = 0; kt < 4; ++kt)
        aP[kt] = ldb(phiu + ((size_t)(t + 1) * B_ + b0 + ln) * H_ + kt * 32 + lq * 8);
    }

    // ---- layer 1: gi1 = h0' @ Wih1^T ; gh1 = h1 @ Whh1^T ----
    bf16v aI[4], aH1[4];
#pragma unroll
    for (int kt = 0; kt < 4; ++kt) {
      aI[kt]  = ldb(&H0[nxt][ln * 136 + kt * 32 + lq * 8]);
      aH1[kt] = ldb(&H1[cur][ln * 136 + kt * 32 + lq * 8]);
    }
    f32x4 dIR = {0,0,0,0}, dIZ = {0,0,0,0}, dIN = {0,0,0,0};
    f32x4 dHR = {0,0,0,0}, dHZ = {0,0,0,0}, dHN = {0,0,0,0};
#pragma unroll
    for (int kt = 0; kt < 4; ++kt) {
      bf16v bHR = ldb(&WH1s[(0 * 128 + f0 + ln) * 136 + kt * 32 + lq * 8]);
      bf16v bHZ = ldb(&WH1s[(1 * 128 + f0 + ln) * 136 + kt * 32 + lq * 8]);
      bf16v bHN = ldb(&WH1s[(2 * 128 + f0 + ln) * 136 + kt * 32 + lq * 8]);
      dIR = MFMA(aI[kt], wI1[0][kt], dIR);
      dIZ = MFMA(aI[kt], wI1[1][kt], dIZ);
      dIN = MFMA(aI[kt], wI1[2][kt], dIN);
      dHR = MFMA(aH1[kt], bHR, dHR);
      dHZ = MFMA(aH1[kt], bHZ, dHZ);
      dHN = MFMA(aH1[kt], bHN, dHN);
    }
#pragma unroll
    for (int j = 0; j < 4; ++j) {
      float r = sigm(dIR[j] + dHR[j]);
      float z = sigm(dIZ[j] + dHZ[j]);
      float n = tanhg(fmaf(r, dHN[j], dIN[j]));
      float h = fmaf(z, h1s[j] - n, n);
      h1s[j] = h;
      H1[nxt][(lq * 4 + j) * 136 + f0 + ln] = f2b(h);
      if (t + 1 < TC)
        h1old[((size_t)(t + 1) * B_ + b0 + lq * 4 + j) * H_ + f0 + ln] = f2b(h);
    }
    // no second barrier: next step's mid barrier orders all remaining hazards
  }

  // persist h state for next chunk
#pragma unroll
  for (int j = 0; j < 4; ++j) {
    int m = lq * 4 + j;
    hst[(size_t)(0 * B_ + b0 + m) * H_ + f0 + ln] = h0s[j];
    hst[(size_t)(1 * B_ + b0 + m) * H_ + f0 + ln] = h1s[j];
  }
}

// ============ kernel 5: post-chain + loss partials (one chunk) ============
DI void layer128(const u16* __restrict__ W, const float* __restrict__ bias,
                 const u16* A, u16* Dst, int dstOff, int nTiles, bool relu,
                 int ln, int lq) {
  bf16v a[2][4];
#pragma unroll
  for (int mt = 0; mt < 2; ++mt)
#pragma unroll
    for (int kt = 0; kt < 4; ++kt)
      a[mt][kt] = ldb(A + (mt * 16 + ln) * 136 + kt * 32 + lq * 8);
  for (int nt = 0; nt < nTiles; ++nt) {
    f32x4 c0 = {0,0,0,0}, c1 = {0,0,0,0};
#pragma unroll
    for (int kt = 0; kt < 4; ++kt) {
      bf16v b = ldb(W + (nt * 16 + ln) * 128 + kt * 32 + lq * 8);
      c0 = MFMA(a[0][kt], b, c0); c1 = MFMA(a[1][kt], b, c1);
    }
    float bv = bias[nt * 16 + ln];
#pragma unroll
    for (int mt = 0; mt < 2; ++mt)
#pragma unroll
      for (int j = 0; j < 4; ++j) {
        float v = (mt ? c1[j] : c0[j]) + bv;
        if (relu) v = fmaxf(v, 0.f);
        Dst[(mt * 16 + lq * 4 + j) * 136 + dstOff + nt * 16 + ln] = f2b(v);
      }
  }
}

__global__ __launch_bounds__(128) void k_post(
    const u16* __restrict__ phiu, const u16* __restrict__ h1old,
    const u16* __restrict__ yT, const u16* __restrict__ wb,
    const float* __restrict__ dy_b1, const float* __restrict__ dy_b2,
    const float* __restrict__ xm_b, const float* __restrict__ xlv_b,
    const float* __restrict__ px_b1, const float* __restrict__ px_b2,
    const float* __restrict__ me_b1, const float* __restrict__ me_b2,
    float* __restrict__ partials, int first) {
  __shared__ __align__(16) u16 buf[2][2][32 * 136];
  __shared__ float wsum[2];
  const int lane = threadIdx.x & 63, w = threadIdx.x >> 6;   // 2 waves
  const int ln = lane & 15, lq = lane >> 4;
  const int r0 = (blockIdx.x * 2 + w) * 32;
  u16* X = buf[w][0];
  u16* Yb = buf[w][1];

  // step 1: dy hidden = relu([phi_u||h1old] @ dy_w1^T + b1), K=256 -> X
  {
    bf16v a[2][8];
#pragma unroll
    for (int mt = 0; mt < 2; ++mt)
#pragma unroll
      for (int kt = 0; kt < 8; ++kt) {
        size_t row = (size_t)(r0 + mt * 16 + ln);
        a[mt][kt] = (kt < 4) ? ldb(phiu + row * H_ + kt * 32 + lq * 8)
                             : ldb(h1old + row * H_ + (kt - 4) * 32 + lq * 8);
      }
    const u16* W = wb + O_DY_W1;
    for (int nt = 0; nt < 8; ++nt) {
      f32x4 c0 = {0,0,0,0}, c1 = {0,0,0,0};
#pragma unroll
      for (int kt = 0; kt < 8; ++kt) {
        bf16v b = ldb(W + (nt * 16 + ln) * 256 + kt * 32 + lq * 8);
        c0 = MFMA(a[0][kt], b, c0); c1 = MFMA(a[1][kt], b, c1);
      }
      float bv = dy_b1[nt * 16 + ln];
#pragma unroll
      for (int mt = 0; mt < 2; ++mt)
#pragma unroll
        for (int j = 0; j < 4; ++j) {
          float v = (mt ? c1[j] : c0[j]) + bv;
          X[(mt * 16 + lq * 4 + j) * 136 + nt * 16 + ln] = f2b(fmaxf(v, 0.f));
        }
    }
  }
  layer128(wb + O_DY_W2, dy_b2, X, Yb, 0, 8, false, ln, lq);   // dphi
  layer128(wb + O_XM_W,  xm_b,  Yb, X, 0, 4, false, ln, lq);   // x_mean   -> X[:,0:64]
  layer128(wb + O_XLV_W, xlv_b, Yb, X, 64, 4, false, ln, lq);  // x_logvar -> X[:,64:128]
  layer128(wb + O_PX_W1, px_b1, X, Yb, 0, 8, true,  ln, lq);   // px hidden
  layer128(wb + O_PX_W2, px_b2, Yb, X, 0, 8, false, ln, lq);   // phi_x
  layer128(wb + O_ME_W1, me_b1, X, Yb, 0, 8, true,  ln, lq);   // me hidden

  // final: y_hat = Yb @ me_w2^T + b2 ; loss += (y_hat - y)^2
  float lsum = 0.f;
  {
    bf16v a[2][4];
#pragma unroll
    for (int mt = 0; mt < 2; ++mt)
#pragma unroll
      for (int kt = 0; kt < 4; ++kt)
        a[mt][kt] = ldb(Yb + (mt * 16 + ln) * 136 + kt * 32 + lq * 8);
    const u16* W = wb + O_ME_W2;
#pragma unroll
    for (int nt = 0; nt < 2; ++nt) {
      f32x4 c0 = {0,0,0,0}, c1 = {0,0,0,0};
#pragma unroll
      for (int kt = 0; kt < 4; ++kt) {
        bf16v b = ldb(W + (nt * 16 + ln) * 128 + kt * 32 + lq * 8);
        c0 = MFMA(a[0][kt], b, c0); c1 = MFMA(a[1][kt], b, c1);
      }
      float bv = me_b2[nt * 16 + ln];
#pragma unroll
      for (int mt = 0; mt < 2; ++mt)
#pragma unroll
        for (int j = 0; j < 4; ++j) {
          int m = mt * 16 + lq * 4 + j;
          float v = (mt ? c1[j] : c0[j]) + bv;
          float yv = b2f(yT[(size_t)(r0 + m) * 32 + nt * 16 + ln]);
          float d = v - yv;
          lsum += d * d;
        }
    }
  }
#pragma unroll
  for (int o = 32; o; o >>= 1) lsum += __shfl_down(lsum, o);
  if (lane == 0) wsum[w] = lsum;
  __syncthreads();
  if (threadIdx.x == 0) {
    float v = wsum[0] + wsum[1];
    if (first) partials[blockIdx.x] = v;
    else       partials[blockIdx.x] += v;
  }
}

// ============ kernel 6: deterministic final reduction ============
__global__ void k_finalize(const float* __restrict__ partials, float* __restrict__ out) {
  __shared__ double s[256];
  double acc = 0.0;
  for (int i = threadIdx.x; i < 1024; i += 256) acc += (double)partials[i];
  s[threadIdx.x] = acc;
  __syncthreads();
  for (int o = 128; o; o >>= 1) {
    if (threadIdx.x < o) s[threadIdx.x] += s[threadIdx.x + o];
    __syncthreads();
  }
  if (threadIdx.x == 0) out[0] = (float)s[0];
}

extern "C" void kernel_launch(void* const* d_in, const int* in_sizes, int n_in,
                              void* d_out, int out_size, void* d_ws, size_t ws_size,
                              hipStream_t stream) {
  const float* u     = (const float*)d_in[0];
  const float* y     = (const float*)d_in[1];
  const float* h0    = (const float*)d_in[2];
  const float* pu_w1 = (const float*)d_in[3];
  const float* pu_b1 = (const float*)d_in[4];
  const float* pu_w2 = (const float*)d_in[5];
  const float* pu_b2 = (const float*)d_in[6];
  const float* dy_w1 = (const float*)d_in[7];
  const float* dy_b1 = (const float*)d_in[8];
  const float* dy_w2 = (const float*)d_in[9];
  const float* dy_b2 = (const float*)d_in[10];
  const float* xm_w  = (const float*)d_in[11];
  const float* xm_b  = (const float*)d_in[12];
  const float* xlv_w = (const float*)d_in[13];
  const float* xlv_b = (const float*)d_in[14];
  const float* px_w1 = (const float*)d_in[15];
  const float* px_b1 = (const float*)d_in[16];
  const float* px_w2 = (const float*)d_in[17];
  const float* px_b2 = (const float*)d_in[18];
  const float* me_w1 = (const float*)d_in[19];
  const float* me_b1 = (const float*)d_in[20];
  const float* me_w2 = (const float*)d_in[21];
  const float* me_b2 = (const float*)d_in[22];
  const float* gih   = (const float*)d_in[23];
  const float* ghh   = (const float*)d_in[24];

  char* ws = (char*)d_ws;
  u16* wb    = (u16*)(ws + WS_WB);
  float* hst = (float*)(ws + WS_HST);
  float* prt = (float*)(ws + WS_PART);
  u16* uT    = (u16*)(ws + WS_UT);
  u16* yT    = (u16*)(ws + WS_YT);
  u16* phiu  = (u16*)(ws + WS_PHIU);
  u16* h1o   = (u16*)(ws + WS_H1);
  float* out = (float*)d_out;

  k_convert_weights<<<256, 256, 0, stream>>>(pu_w1, pu_w2, dy_w1, dy_w2, xm_w, xlv_w,
                                             px_w1, px_w2, me_w1, me_w2, gih, ghh,
                                             h0, wb, hst);
  for (int c = 0; c < NCH; ++c) {
    k_transpose<<<dim3(TC / 32, 256, 2), dim3(32, 8), 0, stream>>>(u, y, uT, yT, c * TC);
    k_phi_u<<<RC / 128, 256, 0, stream>>>(uT, wb, pu_b1, pu_b2, phiu);
    k_gru_seq<<<16, 512, 0, stream>>>(phiu, wb, hst, h1o);
    k_post<<<RC / 64, 128, 0, stream>>>(phiu, h1o, yT, wb, dy_b1, dy_b2, xm_b, xlv_b,
                                        px_b1, px_b2, me_b1, me_b2, prt, c == 0 ? 1 : 0);
  }
  k_finalize<<<1, 256, 0, stream>>>(prt, out);
}

// Round 4
// 4096.737 us; speedup vs baseline: 1.6719x; 1.1351x over previous
//
#include <hip/hip_runtime.h>

#define DI __device__ __forceinline__

typedef unsigned short u16;
typedef __bf16 bf16v __attribute__((ext_vector_type(8)));   // 8 bf16 = 4 VGPRs (MFMA A/B frag)
typedef float f32x4 __attribute__((ext_vector_type(4)));     // MFMA C/D frag

constexpr int B_ = 256, T_ = 2048, U_ = 32, Yd_ = 32, H_ = 128, Z_ = 64;
constexpr int BU = B_ * U_;        // 8192
constexpr int TC = 256;            // time-chunk length
constexpr int NCH = T_ / TC;       // 8 chunks
constexpr int RC = TC * B_;        // rows per chunk = 65536

// ---- bf16 weight pool offsets (elements) ----
constexpr size_t O_PU_W1 = 0;        // [128][32]
constexpr size_t O_PU_W2 = 4096;     // [128][128]
constexpr size_t O_DY_W1 = 20480;    // [128][256]
constexpr size_t O_DY_W2 = 53248;    // [128][128]
constexpr size_t O_XM_W  = 69632;    // [64][128]
constexpr size_t O_XLV_W = 77824;    // [64][128]
constexpr size_t O_PX_W1 = 86016;    // [128][128]
constexpr size_t O_PX_W2 = 102400;   // [128][128]
constexpr size_t O_ME_W1 = 118784;   // [128][128]
constexpr size_t O_ME_W2 = 135168;   // [32][128]
constexpr size_t O_WIH   = 139264;   // [2][384][128]
constexpr size_t O_WHH   = 237568;   // [2][384][128]

// ---- ws byte offsets (total ~42 MiB) ----
constexpr size_t WS_WB   = 0;                                // 672 KiB used
constexpr size_t WS_HST  = 0x100000;                         // h state [2][B][H] f32 (256 KiB)
constexpr size_t WS_PART = 0x140000;                         // 1024 f32 partials
constexpr size_t WS_UT   = 0x180000;                         // u^T chunk [TC][B*32] bf16 (4 MiB)
constexpr size_t WS_YT   = WS_UT + (size_t)RC * 32 * 2;      // y^T chunk (4 MiB)
constexpr size_t WS_PHIU = WS_YT + (size_t)RC * 32 * 2;      // phi_u chunk [RC][128] bf16 (16 MiB)
constexpr size_t WS_H1   = WS_PHIU + (size_t)RC * H_ * 2;    // h1(pre-update) chunk (16 MiB)

DI u16 f2b(float x) {
  union { float f; unsigned u; } v; v.f = x;
  unsigned r = v.u + 0x7fffu + ((v.u >> 16) & 1u);   // RNE
  return (u16)(r >> 16);
}
DI float b2f(u16 h) { union { unsigned u; float f; } v; v.u = ((unsigned)h) << 16; return v.f; }
// select-free fast gates (exp2-based; rcp(inf)=0 handles saturation)
DI float sigm(float x) {
  return __builtin_amdgcn_rcpf(1.f + __builtin_amdgcn_exp2f(-1.44269504f * x));
}
DI float tanhg(float x) {
  return fmaf(2.f, __builtin_amdgcn_rcpf(1.f + __builtin_amdgcn_exp2f(-2.88539008f * x)), -1.f);
}
DI f32x4 MFMA(bf16v a, bf16v b, f32x4 c) {
  return __builtin_amdgcn_mfma_f32_16x16x32_bf16(a, b, c, 0, 0, 0);
}
DI bf16v ldb(const u16* p) { return *reinterpret_cast<const bf16v*>(p); }

// ============ kernel 1: convert weights f32 -> bf16 pool, init h state ============
__global__ void k_convert_weights(
    const float* pu_w1, const float* pu_w2, const float* dy_w1, const float* dy_w2,
    const float* xm_w, const float* xlv_w, const float* px_w1, const float* px_w2,
    const float* me_w1, const float* me_w2, const float* gih, const float* ghh,
    const float* h0, u16* wb, float* hst) {
  int i0 = blockIdx.x * blockDim.x + threadIdx.x;
  int st = gridDim.x * blockDim.x;
#define CVT(src, off, n) for (int i = i0; i < (n); i += st) wb[(off) + i] = f2b(src[i]);
  CVT(pu_w1, O_PU_W1, 4096)  CVT(pu_w2, O_PU_W2, 16384)
  CVT(dy_w1, O_DY_W1, 32768) CVT(dy_w2, O_DY_W2, 16384)
  CVT(xm_w,  O_XM_W,  8192)  CVT(xlv_w, O_XLV_W, 8192)
  CVT(px_w1, O_PX_W1, 16384) CVT(px_w2, O_PX_W2, 16384)
  CVT(me_w1, O_ME_W1, 16384) CVT(me_w2, O_ME_W2, 4096)
  CVT(gih,   O_WIH,   98304) CVT(ghh,   O_WHH,   98304)
#undef CVT
  for (int i = i0; i < 2 * B_ * H_; i += st) hst[i] = h0[i];
}

// ============ kernel 2: transpose u,y slice: [BU][T] f32 -> [TC][BU] bf16 ============
__global__ void k_transpose(const float* __restrict__ u, const float* __restrict__ y,
                            u16* __restrict__ uT, u16* __restrict__ yT, int t0) {
  const float* src = blockIdx.z ? y : u;
  u16* dst = blockIdx.z ? yT : uT;
  __shared__ float tile[32][33];
  const int tx = threadIdx.x, ty = threadIdx.y;      // 32 x 8
  const int c0 = blockIdx.x * 32;                    // t (chunk-local)
  const int r0 = blockIdx.y * 32;                    // b*32+chan
#pragma unroll
  for (int i = 0; i < 4; ++i)
    tile[ty + i * 8][tx] = src[(size_t)(r0 + ty + i * 8) * T_ + t0 + c0 + tx];
  __syncthreads();
#pragma unroll
  for (int i = 0; i < 4; ++i)
    dst[(size_t)(c0 + ty + i * 8) * BU + r0 + tx] = f2b(tile[tx][ty + i * 8]);
}

// ============ kernel 3: phi_u for one chunk (RC rows) ============
__global__ __launch_bounds__(256) void k_phi_u(
    const u16* __restrict__ uT, const u16* __restrict__ wb,
    const float* __restrict__ pu_b1, const float* __restrict__ pu_b2,
    u16* __restrict__ phiu) {
  __shared__ __align__(16) u16 hid[4][32 * 136];
  const int lane = threadIdx.x & 63, w = threadIdx.x >> 6;
  const int ln = lane & 15, lq = lane >> 4;
  const int r0 = (blockIdx.x * 4 + w) * 32;
  u16* hb = hid[w];

  // layer 1: K=32, out 128, relu
  bf16v a0 = ldb(uT + (size_t)(r0 + ln) * 32 + lq * 8);
  bf16v a1 = ldb(uT + (size_t)(r0 + 16 + ln) * 32 + lq * 8);
  const u16* w1 = wb + O_PU_W1;
#pragma unroll
  for (int nt = 0; nt < 8; ++nt) {
    f32x4 c0 = {0.f, 0.f, 0.f, 0.f}, c1 = {0.f, 0.f, 0.f, 0.f};
    bf16v b = ldb(w1 + (nt * 16 + ln) * 32 + lq * 8);
    c0 = MFMA(a0, b, c0); c1 = MFMA(a1, b, c1);
    float bv = pu_b1[nt * 16 + ln];
#pragma unroll
    for (int j = 0; j < 4; ++j) {
      hb[(lq * 4 + j) * 136 + nt * 16 + ln]        = f2b(fmaxf(c0[j] + bv, 0.f));
      hb[(16 + lq * 4 + j) * 136 + nt * 16 + ln]   = f2b(fmaxf(c1[j] + bv, 0.f));
    }
  }
  // layer 2: K=128, out 128 -> global
  bf16v a[2][4];
#pragma unroll
  for (int mt = 0; mt < 2; ++mt)
#pragma unroll
    for (int kt = 0; kt < 4; ++kt)
      a[mt][kt] = ldb(hb + (mt * 16 + ln) * 136 + kt * 32 + lq * 8);
  const u16* w2 = wb + O_PU_W2;
#pragma unroll
  for (int nt = 0; nt < 8; ++nt) {
    f32x4 c0 = {0.f, 0.f, 0.f, 0.f}, c1 = {0.f, 0.f, 0.f, 0.f};
#pragma unroll
    for (int kt = 0; kt < 4; ++kt) {
      bf16v b = ldb(w2 + (nt * 16 + ln) * 128 + kt * 32 + lq * 8);
      c0 = MFMA(a[0][kt], b, c0); c1 = MFMA(a[1][kt], b, c1);
    }
    float bv = pu_b2[nt * 16 + ln];
#pragma unroll
    for (int mt = 0; mt < 2; ++mt)
#pragma unroll
      for (int j = 0; j < 4; ++j) {
        float v = (mt ? c1[j] : c0[j]) + bv;
        phiu[(size_t)(r0 + mt * 16 + lq * 4 + j) * H_ + nt * 16 + ln] = f2b(v);
      }
  }
}

// ============ kernel 4: sequential 2-layer GRU over one chunk, 16 WGs ============
// ALL GRU weights register-resident (48 frags = 192 VGPR); launch_bounds(512,2)
// gives the 256-VGPR budget (only 8 waves/CU exist). One barrier per step.
__global__ __launch_bounds__(512, 2) void k_gru_seq(
    const u16* __restrict__ phiu, const u16* __restrict__ wb,
    float* __restrict__ hst, u16* __restrict__ h1old) {
  __shared__ __align__(16) u16 H0[2][16 * 136];
  __shared__ __align__(16) u16 H1[2][16 * 136];
  const int lane = threadIdx.x & 63, w = threadIdx.x >> 6;   // 8 waves
  const int ln = lane & 15, lq = lane >> 4;
  const int f0 = w * 16;                                      // feature slice
  const int b0 = blockIdx.x * 16;
  const u16* wi0 = wb + O_WIH;
  const u16* wh0 = wb + O_WHH;
  const u16* wi1 = wi0 + 49152;
  const u16* wh1 = wh0 + 49152;

  // preload ALL GRU weights into registers (loop-invariant, 192 VGPR)
  bf16v wI0[3][4], wH0[3][4], wI1[3][4], wH1[3][4];
#pragma unroll
  for (int g = 0; g < 3; ++g)
#pragma unroll
    for (int kt = 0; kt < 4; ++kt) {
      size_t row = (size_t)(g * 128 + f0 + ln);
      size_t col = (size_t)kt * 32 + lq * 8;
      wI0[g][kt] = ldb(wi0 + row * H_ + col);
      wH0[g][kt] = ldb(wh0 + row * H_ + col);
      wI1[g][kt] = ldb(wi1 + row * H_ + col);
      wH1[g][kt] = ldb(wh1 + row * H_ + col);
    }

  float h0s[4], h1s[4];
#pragma unroll
  for (int j = 0; j < 4; ++j) {
    int m = lq * 4 + j;
    h0s[j] = hst[(size_t)(0 * B_ + b0 + m) * H_ + f0 + ln];
    h1s[j] = hst[(size_t)(1 * B_ + b0 + m) * H_ + f0 + ln];
    H0[0][m * 136 + f0 + ln] = f2b(h0s[j]);
    H1[0][m * 136 + f0 + ln] = f2b(h1s[j]);
    h1old[(size_t)(b0 + m) * H_ + f0 + ln] = f2b(h1s[j]);    // chunk-local t = 0 slot
  }

  // prefetch phi_u A-frags for t=0
  bf16v aP[4];
#pragma unroll
  for (int kt = 0; kt < 4; ++kt)
    aP[kt] = ldb(phiu + ((size_t)0 * B_ + b0 + ln) * H_ + kt * 32 + lq * 8);

  __syncthreads();

  for (int t = 0; t < TC; ++t) {
    const int cur = t & 1, nxt = cur ^ 1;
    // ---- layer 0 ---- (r/z gates: i- and h- products share one accumulator)
    f32x4 cR = {0,0,0,0}, cZ = {0,0,0,0}, cIN = {0,0,0,0}, cHN = {0,0,0,0};
#pragma unroll
    for (int kt = 0; kt < 4; ++kt) {
      bf16v aH = ldb(&H0[cur][ln * 136 + kt * 32 + lq * 8]);
      cR  = MFMA(aP[kt], wI0[0][kt], cR);
      cR  = MFMA(aH,     wH0[0][kt], cR);
      cZ  = MFMA(aP[kt], wI0[1][kt], cZ);
      cZ  = MFMA(aH,     wH0[1][kt], cZ);
      cIN = MFMA(aP[kt], wI0[2][kt], cIN);
      cHN = MFMA(aH,     wH0[2][kt], cHN);
    }
#pragma unroll
    for (int j = 0; j < 4; ++j) {
      float r = sigm(cR[j]);
      float z = sigm(cZ[j]);
      float n = tanhg(fmaf(r, cHN[j], cIN[j]));
      float h = fmaf(z, h0s[j] - n, n);
      h0s[j] = h;
      H0[nxt][(lq * 4 + j) * 136 + f0 + ln] = f2b(h);
    }
    __syncthreads();   // the ONLY barrier per step

    // prefetch phi_u for t+1 AFTER the barrier (consumed next step, pre-barrier)
    if (t + 1 < TC) {
#pragma unroll
      for (int kt = 0; kt < 4; ++kt)
        aP[kt] = ldb(phiu + ((size_t)(t + 1) * B_ + b0 + ln) * H_ + kt * 32 + lq * 8);
    }

    // ---- layer 1 ----
    f32x4 dR = {0,0,0,0}, dZ = {0,0,0,0}, dIN = {0,0,0,0}, dHN = {0,0,0,0};
#pragma unroll
    for (int kt = 0; kt < 4; ++kt) {
      bf16v aI  = ldb(&H0[nxt][ln * 136 + kt * 32 + lq * 8]);
      bf16v aH1 = ldb(&H1[cur][ln * 136 + kt * 32 + lq * 8]);
      dR  = MFMA(aI,  wI1[0][kt], dR);
      dR  = MFMA(aH1, wH1[0][kt], dR);
      dZ  = MFMA(aI,  wI1[1][kt], dZ);
      dZ  = MFMA(aH1, wH1[1][kt], dZ);
      dIN = MFMA(aI,  wI1[2][kt], dIN);
      dHN = MFMA(aH1, wH1[2][kt], dHN);
    }
#pragma unroll
    for (int j = 0; j < 4; ++j) {
      float r = sigm(dR[j]);
      float z = sigm(dZ[j]);
      float n = tanhg(fmaf(r, dHN[j], dIN[j]));
      float h = fmaf(z, h1s[j] - n, n);
      h1s[j] = h;
      H1[nxt][(lq * 4 + j) * 136 + f0 + ln] = f2b(h);
      if (t + 1 < TC)
        h1old[((size_t)(t + 1) * B_ + b0 + lq * 4 + j) * H_ + f0 + ln] = f2b(h);
    }
    // no second barrier: next step's mid barrier orders all remaining hazards
  }

  // persist h state for next chunk
#pragma unroll
  for (int j = 0; j < 4; ++j) {
    int m = lq * 4 + j;
    hst[(size_t)(0 * B_ + b0 + m) * H_ + f0 + ln] = h0s[j];
    hst[(size_t)(1 * B_ + b0 + m) * H_ + f0 + ln] = h1s[j];
  }
}

// ============ kernel 5: post-chain + loss partials (one chunk) ============
DI void layer128(const u16* __restrict__ W, const float* __restrict__ bias,
                 const u16* A, u16* Dst, int dstOff, int nTiles, bool relu,
                 int ln, int lq) {
  bf16v a[2][4];
#pragma unroll
  for (int mt = 0; mt < 2; ++mt)
#pragma unroll
    for (int kt = 0; kt < 4; ++kt)
      a[mt][kt] = ldb(A + (mt * 16 + ln) * 136 + kt * 32 + lq * 8);
  for (int nt = 0; nt < nTiles; ++nt) {
    f32x4 c0 = {0,0,0,0}, c1 = {0,0,0,0};
#pragma unroll
    for (int kt = 0; kt < 4; ++kt) {
      bf16v b = ldb(W + (nt * 16 + ln) * 128 + kt * 32 + lq * 8);
      c0 = MFMA(a[0][kt], b, c0); c1 = MFMA(a[1][kt], b, c1);
    }
    float bv = bias[nt * 16 + ln];
#pragma unroll
    for (int mt = 0; mt < 2; ++mt)
#pragma unroll
      for (int j = 0; j < 4; ++j) {
        float v = (mt ? c1[j] : c0[j]) + bv;
        if (relu) v = fmaxf(v, 0.f);
        Dst[(mt * 16 + lq * 4 + j) * 136 + dstOff + nt * 16 + ln] = f2b(v);
      }
  }
}

__global__ __launch_bounds__(128) void k_post(
    const u16* __restrict__ phiu, const u16* __restrict__ h1old,
    const u16* __restrict__ yT, const u16* __restrict__ wb,
    const float* __restrict__ dy_b1, const float* __restrict__ dy_b2,
    const float* __restrict__ xm_b, const float* __restrict__ xlv_b,
    const float* __restrict__ px_b1, const float* __restrict__ px_b2,
    const float* __restrict__ me_b1, const float* __restrict__ me_b2,
    float* __restrict__ partials, int first) {
  __shared__ __align__(16) u16 buf[2][2][32 * 136];
  __shared__ float wsum[2];
  const int lane = threadIdx.x & 63, w = threadIdx.x >> 6;   // 2 waves
  const int ln = lane & 15, lq = lane >> 4;
  const int r0 = (blockIdx.x * 2 + w) * 32;
  u16* X = buf[w][0];
  u16* Yb = buf[w][1];

  // step 1: dy hidden = relu([phi_u||h1old] @ dy_w1^T + b1), K=256 -> X
  {
    bf16v a[2][8];
#pragma unroll
    for (int mt = 0; mt < 2; ++mt)
#pragma unroll
      for (int kt = 0; kt < 8; ++kt) {
        size_t row = (size_t)(r0 + mt * 16 + ln);
        a[mt][kt] = (kt < 4) ? ldb(phiu + row * H_ + kt * 32 + lq * 8)
                             : ldb(h1old + row * H_ + (kt - 4) * 32 + lq * 8);
      }
    const u16* W = wb + O_DY_W1;
    for (int nt = 0; nt < 8; ++nt) {
      f32x4 c0 = {0,0,0,0}, c1 = {0,0,0,0};
#pragma unroll
      for (int kt = 0; kt < 8; ++kt) {
        bf16v b = ldb(W + (nt * 16 + ln) * 256 + kt * 32 + lq * 8);
        c0 = MFMA(a[0][kt], b, c0); c1 = MFMA(a[1][kt], b, c1);
      }
      float bv = dy_b1[nt * 16 + ln];
#pragma unroll
      for (int mt = 0; mt < 2; ++mt)
#pragma unroll
        for (int j = 0; j < 4; ++j) {
          float v = (mt ? c1[j] : c0[j]) + bv;
          X[(mt * 16 + lq * 4 + j) * 136 + nt * 16 + ln] = f2b(fmaxf(v, 0.f));
        }
    }
  }
  layer128(wb + O_DY_W2, dy_b2, X, Yb, 0, 8, false, ln, lq);   // dphi
  layer128(wb + O_XM_W,  xm_b,  Yb, X, 0, 4, false, ln, lq);   // x_mean   -> X[:,0:64]
  layer128(wb + O_XLV_W, xlv_b, Yb, X, 64, 4, false, ln, lq);  // x_logvar -> X[:,64:128]
  layer128(wb + O_PX_W1, px_b1, X, Yb, 0, 8, true,  ln, lq);   // px hidden
  layer128(wb + O_PX_W2, px_b2, Yb, X, 0, 8, false, ln, lq);   // phi_x
  layer128(wb + O_ME_W1, me_b1, X, Yb, 0, 8, true,  ln, lq);   // me hidden

  // final: y_hat = Yb @ me_w2^T + b2 ; loss += (y_hat - y)^2
  float lsum = 0.f;
  {
    bf16v a[2][4];
#pragma unroll
    for (int mt = 0; mt < 2; ++mt)
#pragma unroll
      for (int kt = 0; kt < 4; ++kt)
        a[mt][kt] = ldb(Yb + (mt * 16 + ln) * 136 + kt * 32 + lq * 8);
    const u16* W = wb + O_ME_W2;
#pragma unroll
    for (int nt = 0; nt < 2; ++nt) {
      f32x4 c0 = {0,0,0,0}, c1 = {0,0,0,0};
#pragma unroll
      for (int kt = 0; kt < 4; ++kt) {
        bf16v b = ldb(W + (nt * 16 + ln) * 128 + kt * 32 + lq * 8);
        c0 = MFMA(a[0][kt], b, c0); c1 = MFMA(a[1][kt], b, c1);
      }
      float bv = me_b2[nt * 16 + ln];
#pragma unroll
      for (int mt = 0; mt < 2; ++mt)
#pragma unroll
        for (int j = 0; j < 4; ++j) {
          int m = mt * 16 + lq * 4 + j;
          float v = (mt ? c1[j] : c0[j]) + bv;
          float yv = b2f(yT[(size_t)(r0 + m) * 32 + nt * 16 + ln]);
          float d = v - yv;
          lsum += d * d;
        }
    }
  }
#pragma unroll
  for (int o = 32; o; o >>= 1) lsum += __shfl_down(lsum, o);
  if (lane == 0) wsum[w] = lsum;
  __syncthreads();
  if (threadIdx.x == 0) {
    float v = wsum[0] + wsum[1];
    if (first) partials[blockIdx.x] = v;
    else       partials[blockIdx.x] += v;
  }
}

// ============ kernel 6: deterministic final reduction ============
__global__ void k_finalize(const float* __restrict__ partials, float* __restrict__ out) {
  __shared__ double s[256];
  double acc = 0.0;
  for (int i = threadIdx.x; i < 1024; i += 256) acc += (double)partials[i];
  s[threadIdx.x] = acc;
  __syncthreads();
  for (int o = 128; o; o >>= 1) {
    if (threadIdx.x < o) s[threadIdx.x] += s[threadIdx.x + o];
    __syncthreads();
  }
  if (threadIdx.x == 0) out[0] = (float)s[0];
}

extern "C" void kernel_launch(void* const* d_in, const int* in_sizes, int n_in,
                              void* d_out, int out_size, void* d_ws, size_t ws_size,
                              hipStream_t stream) {
  const float* u     = (const float*)d_in[0];
  const float* y     = (const float*)d_in[1];
  const float* h0    = (const float*)d_in[2];
  const float* pu_w1 = (const float*)d_in[3];
  const float* pu_b1 = (const float*)d_in[4];
  const float* pu_w2 = (const float*)d_in[5];
  const float* pu_b2 = (const float*)d_in[6];
  const float* dy_w1 = (const float*)d_in[7];
  const float* dy_b1 = (const float*)d_in[8];
  const float* dy_w2 = (const float*)d_in[9];
  const float* dy_b2 = (const float*)d_in[10];
  const float* xm_w  = (const float*)d_in[11];
  const float* xm_b  = (const float*)d_in[12];
  const float* xlv_w = (const float*)d_in[13];
  const float* xlv_b = (const float*)d_in[14];
  const float* px_w1 = (const float*)d_in[15];
  const float* px_b1 = (const float*)d_in[16];
  const float* px_w2 = (const float*)d_in[17];
  const float* px_b2 = (const float*)d_in[18];
  const float* me_w1 = (const float*)d_in[19];
  const float* me_b1 = (const float*)d_in[20];
  const float* me_w2 = (const float*)d_in[21];
  const float* me_b2 = (const float*)d_in[22];
  const float* gih   = (const float*)d_in[23];
  const float* ghh   = (const float*)d_in[24];

  char* ws = (char*)d_ws;
  u16* wb    = (u16*)(ws + WS_WB);
  float* hst = (float*)(ws + WS_HST);
  float* prt = (float*)(ws + WS_PART);
  u16* uT    = (u16*)(ws + WS_UT);
  u16* yT    = (u16*)(ws + WS_YT);
  u16* phiu  = (u16*)(ws + WS_PHIU);
  u16* h1o   = (u16*)(ws + WS_H1);
  float* out = (float*)d_out;

  k_convert_weights<<<256, 256, 0, stream>>>(pu_w1, pu_w2, dy_w1, dy_w2, xm_w, xlv_w,
                                             px_w1, px_w2, me_w1, me_w2, gih, ghh,
                                             h0, wb, hst);
  for (int c = 0; c < NCH; ++c) {
    k_transpose<<<dim3(TC / 32, 256, 2), dim3(32, 8), 0, stream>>>(u, y, uT, yT, c * TC);
    k_phi_u<<<RC / 128, 256, 0, stream>>>(uT, wb, pu_b1, pu_b2, phiu);
    k_gru_seq<<<16, 512, 0, stream>>>(phiu, wb, hst, h1o);
    k_post<<<RC / 64, 128, 0, stream>>>(phiu, h1o, yT, wb, dy_b1, dy_b2, xm_b, xlv_b,
                                        px_b1, px_b2, me_b1, me_b2, prt, c == 0 ? 1 : 0);
  }
  k_finalize<<<1, 256, 0, stream>>>(prt, out);
}

// Round 5
// 4020.023 us; speedup vs baseline: 1.7038x; 1.0191x over previous
//
#include <hip/hip_runtime.h>

#define DI __device__ __forceinline__

typedef unsigned short u16;
typedef unsigned long long u64;
typedef __bf16 bf16v __attribute__((ext_vector_type(8)));   // 8 bf16 = 4 VGPRs (MFMA A/B frag)
typedef float f32x4 __attribute__((ext_vector_type(4)));     // MFMA C/D frag

constexpr int B_ = 256, T_ = 2048, U_ = 32, Yd_ = 32, H_ = 128, Z_ = 64;
constexpr int BU = B_ * U_;        // 8192
constexpr int TC = 256;            // time-chunk length
constexpr int NCH = T_ / TC;       // 8 chunks
constexpr int RC = TC * B_;        // rows per chunk = 65536

// ---- bf16 weight pool offsets (elements) ----
constexpr size_t O_PU_W1 = 0;        // [128][32]
constexpr size_t O_PU_W2 = 4096;     // [128][128]
constexpr size_t O_DY_W1 = 20480;    // [128][256]
constexpr size_t O_DY_W2 = 53248;    // [128][128]
constexpr size_t O_XM_W  = 69632;    // [64][128]
constexpr size_t O_XLV_W = 77824;    // [64][128]
constexpr size_t O_PX_W1 = 86016;    // [128][128]
constexpr size_t O_PX_W2 = 102400;   // [128][128]
constexpr size_t O_ME_W1 = 118784;   // [128][128]
constexpr size_t O_ME_W2 = 135168;   // [32][128]
constexpr size_t O_WIH   = 139264;   // [2][384][128]
constexpr size_t O_WHH   = 237568;   // [2][384][128]

// ---- ws byte offsets (total ~42 MiB) ----
constexpr size_t WS_WB   = 0;                                // 672 KiB used
constexpr size_t WS_HST  = 0x100000;                         // h state [2][B][H] f32 (256 KiB)
constexpr size_t WS_PART = 0x140000;                         // 1024 f32 partials
constexpr size_t WS_UT   = 0x180000;                         // u^T chunk [TC][B*32] bf16 (4 MiB)
constexpr size_t WS_YT   = WS_UT + (size_t)RC * 32 * 2;      // y^T chunk (4 MiB)
constexpr size_t WS_PHIU = WS_YT + (size_t)RC * 32 * 2;      // phi_u chunk [RC][128] bf16 (16 MiB)
constexpr size_t WS_H1   = WS_PHIU + (size_t)RC * H_ * 2;    // h1(pre-update) chunk (16 MiB)

DI u16 f2b(float x) {
  union { float f; unsigned u; } v; v.f = x;
  unsigned r = v.u + 0x7fffu + ((v.u >> 16) & 1u);   // RNE
  return (u16)(r >> 16);
}
DI float b2f(u16 h) { union { unsigned u; float f; } v; v.u = ((unsigned)h) << 16; return v.f; }
// select-free fast gates (exp2-based; rcp(inf)=0 handles saturation)
DI float sigm(float x) {
  return __builtin_amdgcn_rcpf(1.f + __builtin_amdgcn_exp2f(-1.44269504f * x));
}
DI float tanhg(float x) {
  return fmaf(2.f, __builtin_amdgcn_rcpf(1.f + __builtin_amdgcn_exp2f(-2.88539008f * x)), -1.f);
}
DI f32x4 MFMA(bf16v a, bf16v b, f32x4 c) {
  return __builtin_amdgcn_mfma_f32_16x16x32_bf16(a, b, c, 0, 0, 0);
}
DI bf16v ldb(const u16* p) { return *reinterpret_cast<const bf16v*>(p); }

// ============ kernel 1: convert weights f32 -> bf16 pool, init h state ============
__global__ void k_convert_weights(
    const float* pu_w1, const float* pu_w2, const float* dy_w1, const float* dy_w2,
    const float* xm_w, const float* xlv_w, const float* px_w1, const float* px_w2,
    const float* me_w1, const float* me_w2, const float* gih, const float* ghh,
    const float* h0, u16* wb, float* hst) {
  int i0 = blockIdx.x * blockDim.x + threadIdx.x;
  int st = gridDim.x * blockDim.x;
#define CVT(src, off, n) for (int i = i0; i < (n); i += st) wb[(off) + i] = f2b(src[i]);
  CVT(pu_w1, O_PU_W1, 4096)  CVT(pu_w2, O_PU_W2, 16384)
  CVT(dy_w1, O_DY_W1, 32768) CVT(dy_w2, O_DY_W2, 16384)
  CVT(xm_w,  O_XM_W,  8192)  CVT(xlv_w, O_XLV_W, 8192)
  CVT(px_w1, O_PX_W1, 16384) CVT(px_w2, O_PX_W2, 16384)
  CVT(me_w1, O_ME_W1, 16384) CVT(me_w2, O_ME_W2, 4096)
  CVT(gih,   O_WIH,   98304) CVT(ghh,   O_WHH,   98304)
#undef CVT
  for (int i = i0; i < 2 * B_ * H_; i += st) hst[i] = h0[i];
}

// ============ kernel 2: transpose u,y slice: [BU][T] f32 -> [TC][BU] bf16 ============
__global__ void k_transpose(const float* __restrict__ u, const float* __restrict__ y,
                            u16* __restrict__ uT, u16* __restrict__ yT, int t0) {
  const float* src = blockIdx.z ? y : u;
  u16* dst = blockIdx.z ? yT : uT;
  __shared__ float tile[32][33];
  const int tx = threadIdx.x, ty = threadIdx.y;      // 32 x 8
  const int c0 = blockIdx.x * 32;                    // t (chunk-local)
  const int r0 = blockIdx.y * 32;                    // b*32+chan
#pragma unroll
  for (int i = 0; i < 4; ++i)
    tile[ty + i * 8][tx] = src[(size_t)(r0 + ty + i * 8) * T_ + t0 + c0 + tx];
  __syncthreads();
#pragma unroll
  for (int i = 0; i < 4; ++i)
    dst[(size_t)(c0 + ty + i * 8) * BU + r0 + tx] = f2b(tile[tx][ty + i * 8]);
}

// ============ kernel 3: phi_u for one chunk (RC rows) ============
__global__ __launch_bounds__(256) void k_phi_u(
    const u16* __restrict__ uT, const u16* __restrict__ wb,
    const float* __restrict__ pu_b1, const float* __restrict__ pu_b2,
    u16* __restrict__ phiu) {
  __shared__ __align__(16) u16 hid[4][32 * 136];
  const int lane = threadIdx.x & 63, w = threadIdx.x >> 6;
  const int ln = lane & 15, lq = lane >> 4;
  const int r0 = (blockIdx.x * 4 + w) * 32;
  u16* hb = hid[w];

  // layer 1: K=32, out 128, relu
  bf16v a0 = ldb(uT + (size_t)(r0 + ln) * 32 + lq * 8);
  bf16v a1 = ldb(uT + (size_t)(r0 + 16 + ln) * 32 + lq * 8);
  const u16* w1 = wb + O_PU_W1;
#pragma unroll
  for (int nt = 0; nt < 8; ++nt) {
    f32x4 c0 = {0.f, 0.f, 0.f, 0.f}, c1 = {0.f, 0.f, 0.f, 0.f};
    bf16v b = ldb(w1 + (nt * 16 + ln) * 32 + lq * 8);
    c0 = MFMA(a0, b, c0); c1 = MFMA(a1, b, c1);
    float bv = pu_b1[nt * 16 + ln];
#pragma unroll
    for (int j = 0; j < 4; ++j) {
      hb[(lq * 4 + j) * 136 + nt * 16 + ln]        = f2b(fmaxf(c0[j] + bv, 0.f));
      hb[(16 + lq * 4 + j) * 136 + nt * 16 + ln]   = f2b(fmaxf(c1[j] + bv, 0.f));
    }
  }
  // layer 2: K=128, out 128 -> global
  bf16v a[2][4];
#pragma unroll
  for (int mt = 0; mt < 2; ++mt)
#pragma unroll
    for (int kt = 0; kt < 4; ++kt)
      a[mt][kt] = ldb(hb + (mt * 16 + ln) * 136 + kt * 32 + lq * 8);
  const u16* w2 = wb + O_PU_W2;
#pragma unroll
  for (int nt = 0; nt < 8; ++nt) {
    f32x4 c0 = {0.f, 0.f, 0.f, 0.f}, c1 = {0.f, 0.f, 0.f, 0.f};
#pragma unroll
    for (int kt = 0; kt < 4; ++kt) {
      bf16v b = ldb(w2 + (nt * 16 + ln) * 128 + kt * 32 + lq * 8);
      c0 = MFMA(a[0][kt], b, c0); c1 = MFMA(a[1][kt], b, c1);
    }
    float bv = pu_b2[nt * 16 + ln];
#pragma unroll
    for (int mt = 0; mt < 2; ++mt)
#pragma unroll
      for (int j = 0; j < 4; ++j) {
        float v = (mt ? c1[j] : c0[j]) + bv;
        phiu[(size_t)(r0 + mt * 16 + lq * 4 + j) * H_ + nt * 16 + ln] = f2b(v);
      }
  }
}

// ============ kernel 4: sequential 2-layer GRU over one chunk, 16 WGs ============
// Swapped MFMA operands: D rows = features, D cols = batch. Each thread owns
// batch=ln, features f0+lq*4..+3 (contiguous) -> packed b64 LDS/global writes.
// Weights pinned in VGPRs via asm keep-alive (defeats load-sinking; VGPR~245).
__global__ __launch_bounds__(512, 2) void k_gru_seq(
    const u16* __restrict__ phiu, const u16* __restrict__ wb,
    float* __restrict__ hst, u16* __restrict__ h1old) {
  __shared__ __align__(16) u16 H0[2][16 * 136];
  __shared__ __align__(16) u16 H1[2][16 * 136];
  const int lane = threadIdx.x & 63, w = threadIdx.x >> 6;   // 8 waves
  const int ln = lane & 15, lq = lane >> 4;
  const int f0 = w * 16;                                      // feature slice
  const int fme = f0 + lq * 4;                                // this thread's 4 features
  const int b0 = blockIdx.x * 16;
  const u16* wi0 = wb + O_WIH;
  const u16* wh0 = wb + O_WHH;
  const u16* wi1 = wi0 + 49152;
  const u16* wh1 = wh0 + 49152;

  // preload ALL GRU weights into registers (loop-invariant, 192 VGPR)
  bf16v wI0[3][4], wH0[3][4], wI1[3][4], wH1[3][4];
#pragma unroll
  for (int g = 0; g < 3; ++g)
#pragma unroll
    for (int kt = 0; kt < 4; ++kt) {
      size_t row = (size_t)(g * 128 + f0 + ln);
      size_t col = (size_t)kt * 32 + lq * 8;
      wI0[g][kt] = ldb(wi0 + row * H_ + col);
      wH0[g][kt] = ldb(wh0 + row * H_ + col);
      wI1[g][kt] = ldb(wi1 + row * H_ + col);
      wH1[g][kt] = ldb(wh1 + row * H_ + col);
    }
  // pin: opaque asm prevents rematerialization/sinking of the loads above
#pragma unroll
  for (int g = 0; g < 3; ++g)
#pragma unroll
    for (int kt = 0; kt < 4; ++kt)
      asm volatile("" : "+v"(wI0[g][kt]), "+v"(wH0[g][kt]),
                        "+v"(wI1[g][kt]), "+v"(wH1[g][kt]));

  // per-thread state: h[layer][batch=ln][feature=fme+j]
  float h0s[4], h1s[4];
  {
    union { u64 q; u16 s[4]; } p0, p1;
#pragma unroll
    for (int j = 0; j < 4; ++j) {
      h0s[j] = hst[(size_t)(0 * B_ + b0 + ln) * H_ + fme + j];
      h1s[j] = hst[(size_t)(1 * B_ + b0 + ln) * H_ + fme + j];
      p0.s[j] = f2b(h0s[j]);
      p1.s[j] = f2b(h1s[j]);
    }
    *reinterpret_cast<u64*>(&H0[0][ln * 136 + fme]) = p0.q;
    *reinterpret_cast<u64*>(&H1[0][ln * 136 + fme]) = p1.q;
    *reinterpret_cast<u64*>(&h1old[(size_t)(b0 + ln) * H_ + fme]) = p1.q;  // t=0 slot
  }

  // prefetch phi_u B-frags for t=0 (batch rows, row=ln)
  bf16v aP[4];
#pragma unroll
  for (int kt = 0; kt < 4; ++kt)
    aP[kt] = ldb(phiu + ((size_t)0 * B_ + b0 + ln) * H_ + kt * 32 + lq * 8);

  __syncthreads();

  for (int t = 0; t < TC; ++t) {
    const int cur = t & 1, nxt = cur ^ 1;
    // ---- layer 0 ---- A=weights(features), B=h/phi_u(batch)
    f32x4 cR = {0,0,0,0}, cZ = {0,0,0,0}, cIN = {0,0,0,0}, cHN = {0,0,0,0};
#pragma unroll
    for (int kt = 0; kt < 4; ++kt) {
      bf16v aH = ldb(&H0[cur][ln * 136 + kt * 32 + lq * 8]);
      cR  = MFMA(wI0[0][kt], aP[kt], cR);
      cR  = MFMA(wH0[0][kt], aH,     cR);
      cZ  = MFMA(wI0[1][kt], aP[kt], cZ);
      cZ  = MFMA(wH0[1][kt], aH,     cZ);
      cIN = MFMA(wI0[2][kt], aP[kt], cIN);
      cHN = MFMA(wH0[2][kt], aH,     cHN);
    }
    {
      union { u64 q; u16 s[4]; } pk;
#pragma unroll
      for (int j = 0; j < 4; ++j) {
        float r = sigm(cR[j]);
        float z = sigm(cZ[j]);
        float n = tanhg(fmaf(r, cHN[j], cIN[j]));
        float h = fmaf(z, h0s[j] - n, n);
        h0s[j] = h;
        pk.s[j] = f2b(h);
      }
      *reinterpret_cast<u64*>(&H0[nxt][ln * 136 + fme]) = pk.q;
    }
    __syncthreads();   // the ONLY barrier per step

    // prefetch phi_u for t+1 AFTER the barrier (consumed next step, pre-barrier)
    if (t + 1 < TC) {
#pragma unroll
      for (int kt = 0; kt < 4; ++kt)
        aP[kt] = ldb(phiu + ((size_t)(t + 1) * B_ + b0 + ln) * H_ + kt * 32 + lq * 8);
    }

    // ---- layer 1 ----
    f32x4 dR = {0,0,0,0}, dZ = {0,0,0,0}, dIN = {0,0,0,0}, dHN = {0,0,0,0};
#pragma unroll
    for (int kt = 0; kt < 4; ++kt) {
      bf16v aI  = ldb(&H0[nxt][ln * 136 + kt * 32 + lq * 8]);
      bf16v aH1 = ldb(&H1[cur][ln * 136 + kt * 32 + lq * 8]);
      dR  = MFMA(wI1[0][kt], aI,  dR);
      dR  = MFMA(wH1[0][kt], aH1, dR);
      dZ  = MFMA(wI1[1][kt], aI,  dZ);
      dZ  = MFMA(wH1[1][kt], aH1, dZ);
      dIN = MFMA(wI1[2][kt], aI,  dIN);
      dHN = MFMA(wH1[2][kt], aH1, dHN);
    }
    {
      union { u64 q; u16 s[4]; } pk;
#pragma unroll
      for (int j = 0; j < 4; ++j) {
        float r = sigm(dR[j]);
        float z = sigm(dZ[j]);
        float n = tanhg(fmaf(r, dHN[j], dIN[j]));
        float h = fmaf(z, h1s[j] - n, n);
        h1s[j] = h;
        pk.s[j] = f2b(h);
      }
      *reinterpret_cast<u64*>(&H1[nxt][ln * 136 + fme]) = pk.q;
      if (t + 1 < TC)
        *reinterpret_cast<u64*>(
            &h1old[((size_t)(t + 1) * B_ + b0 + ln) * H_ + fme]) = pk.q;
    }
    // no second barrier: next step's mid barrier orders all remaining hazards
  }

  // persist h state for next chunk
#pragma unroll
  for (int j = 0; j < 4; ++j) {
    hst[(size_t)(0 * B_ + b0 + ln) * H_ + fme + j] = h0s[j];
    hst[(size_t)(1 * B_ + b0 + ln) * H_ + fme + j] = h1s[j];
  }
}

// ============ kernel 5: post-chain + loss partials (one chunk) ============
DI void layer128(const u16* __restrict__ W, const float* __restrict__ bias,
                 const u16* A, u16* Dst, int dstOff, int nTiles, bool relu,
                 int ln, int lq) {
  bf16v a[2][4];
#pragma unroll
  for (int mt = 0; mt < 2; ++mt)
#pragma unroll
    for (int kt = 0; kt < 4; ++kt)
      a[mt][kt] = ldb(A + (mt * 16 + ln) * 136 + kt * 32 + lq * 8);
  for (int nt = 0; nt < nTiles; ++nt) {
    f32x4 c0 = {0,0,0,0}, c1 = {0,0,0,0};
#pragma unroll
    for (int kt = 0; kt < 4; ++kt) {
      bf16v b = ldb(W + (nt * 16 + ln) * 128 + kt * 32 + lq * 8);
      c0 = MFMA(a[0][kt], b, c0); c1 = MFMA(a[1][kt], b, c1);
    }
    float bv = bias[nt * 16 + ln];
#pragma unroll
    for (int mt = 0; mt < 2; ++mt)
#pragma unroll
      for (int j = 0; j < 4; ++j) {
        float v = (mt ? c1[j] : c0[j]) + bv;
        if (relu) v = fmaxf(v, 0.f);
        Dst[(mt * 16 + lq * 4 + j) * 136 + dstOff + nt * 16 + ln] = f2b(v);
      }
  }
}

__global__ __launch_bounds__(128) void k_post(
    const u16* __restrict__ phiu, const u16* __restrict__ h1old,
    const u16* __restrict__ yT, const u16* __restrict__ wb,
    const float* __restrict__ dy_b1, const float* __restrict__ dy_b2,
    const float* __restrict__ xm_b, const float* __restrict__ xlv_b,
    const float* __restrict__ px_b1, const float* __restrict__ px_b2,
    const float* __restrict__ me_b1, const float* __restrict__ me_b2,
    float* __restrict__ partials, int first) {
  __shared__ __align__(16) u16 buf[2][2][32 * 136];
  __shared__ float wsum[2];
  const int lane = threadIdx.x & 63, w = threadIdx.x >> 6;   // 2 waves
  const int ln = lane & 15, lq = lane >> 4;
  const int r0 = (blockIdx.x * 2 + w) * 32;
  u16* X = buf[w][0];
  u16* Yb = buf[w][1];

  // step 1: dy hidden = relu([phi_u||h1old] @ dy_w1^T + b1), K=256 -> X
  {
    bf16v a[2][8];
#pragma unroll
    for (int mt = 0; mt < 2; ++mt)
#pragma unroll
      for (int kt = 0; kt < 8; ++kt) {
        size_t row = (size_t)(r0 + mt * 16 + ln);
        a[mt][kt] = (kt < 4) ? ldb(phiu + row * H_ + kt * 32 + lq * 8)
                             : ldb(h1old + row * H_ + (kt - 4) * 32 + lq * 8);
      }
    const u16* W = wb + O_DY_W1;
    for (int nt = 0; nt < 8; ++nt) {
      f32x4 c0 = {0,0,0,0}, c1 = {0,0,0,0};
#pragma unroll
      for (int kt = 0; kt < 8; ++kt) {
        bf16v b = ldb(W + (nt * 16 + ln) * 256 + kt * 32 + lq * 8);
        c0 = MFMA(a[0][kt], b, c0); c1 = MFMA(a[1][kt], b, c1);
      }
      float bv = dy_b1[nt * 16 + ln];
#pragma unroll
      for (int mt = 0; mt < 2; ++mt)
#pragma unroll
        for (int j = 0; j < 4; ++j) {
          float v = (mt ? c1[j] : c0[j]) + bv;
          X[(mt * 16 + lq * 4 + j) * 136 + nt * 16 + ln] = f2b(fmaxf(v, 0.f));
        }
    }
  }
  layer128(wb + O_DY_W2, dy_b2, X, Yb, 0, 8, false, ln, lq);   // dphi
  layer128(wb + O_XM_W,  xm_b,  Yb, X, 0, 4, false, ln, lq);   // x_mean   -> X[:,0:64]
  layer128(wb + O_XLV_W, xlv_b, Yb, X, 64, 4, false, ln, lq);  // x_logvar -> X[:,64:128]
  layer128(wb + O_PX_W1, px_b1, X, Yb, 0, 8, true,  ln, lq);   // px hidden
  layer128(wb + O_PX_W2, px_b2, Yb, X, 0, 8, false, ln, lq);   // phi_x
  layer128(wb + O_ME_W1, me_b1, X, Yb, 0, 8, true,  ln, lq);   // me hidden

  // final: y_hat = Yb @ me_w2^T + b2 ; loss += (y_hat - y)^2
  float lsum = 0.f;
  {
    bf16v a[2][4];
#pragma unroll
    for (int mt = 0; mt < 2; ++mt)
#pragma unroll
      for (int kt = 0; kt < 4; ++kt)
        a[mt][kt] = ldb(Yb + (mt * 16 + ln) * 136 + kt * 32 + lq * 8);
    const u16* W = wb + O_ME_W2;
#pragma unroll
    for (int nt = 0; nt < 2; ++nt) {
      f32x4 c0 = {0,0,0,0}, c1 = {0,0,0,0};
#pragma unroll
      for (int kt = 0; kt < 4; ++kt) {
        bf16v b = ldb(W + (nt * 16 + ln) * 128 + kt * 32 + lq * 8);
        c0 = MFMA(a[0][kt], b, c0); c1 = MFMA(a[1][kt], b, c1);
      }
      float bv = me_b2[nt * 16 + ln];
#pragma unroll
      for (int mt = 0; mt < 2; ++mt)
#pragma unroll
        for (int j = 0; j < 4; ++j) {
          int m = mt * 16 + lq * 4 + j;
          float v = (mt ? c1[j] : c0[j]) + bv;
          float yv = b2f(yT[(size_t)(r0 + m) * 32 + nt * 16 + ln]);
          float d = v - yv;
          lsum += d * d;
        }
    }
  }
#pragma unroll
  for (int o = 32; o; o >>= 1) lsum += __shfl_down(lsum, o);
  if (lane == 0) wsum[w] = lsum;
  __syncthreads();
  if (threadIdx.x == 0) {
    float v = wsum[0] + wsum[1];
    if (first) partials[blockIdx.x] = v;
    else       partials[blockIdx.x] += v;
  }
}

// ============ kernel 6: deterministic final reduction ============
__global__ void k_finalize(const float* __restrict__ partials, float* __restrict__ out) {
  __shared__ double s[256];
  double acc = 0.0;
  for (int i = threadIdx.x; i < 1024; i += 256) acc += (double)partials[i];
  s[threadIdx.x] = acc;
  __syncthreads();
  for (int o = 128; o; o >>= 1) {
    if (threadIdx.x < o) s[threadIdx.x] += s[threadIdx.x + o];
    __syncthreads();
  }
  if (threadIdx.x == 0) out[0] = (float)s[0];
}

extern "C" void kernel_launch(void* const* d_in, const int* in_sizes, int n_in,
                              void* d_out, int out_size, void* d_ws, size_t ws_size,
                              hipStream_t stream) {
  const float* u     = (const float*)d_in[0];
  const float* y     = (const float*)d_in[1];
  const float* h0    = (const float*)d_in[2];
  const float* pu_w1 = (const float*)d_in[3];
  const float* pu_b1 = (const float*)d_in[4];
  const float* pu_w2 = (const float*)d_in[5];
  const float* pu_b2 = (const float*)d_in[6];
  const float* dy_w1 = (const float*)d_in[7];
  const float* dy_b1 = (const float*)d_in[8];
  const float* dy_w2 = (const float*)d_in[9];
  const float* dy_b2 = (const float*)d_in[10];
  const float* xm_w  = (const float*)d_in[11];
  const float* xm_b  = (const float*)d_in[12];
  const float* xlv_w = (const float*)d_in[13];
  const float* xlv_b = (const float*)d_in[14];
  const float* px_w1 = (const float*)d_in[15];
  const float* px_b1 = (const float*)d_in[16];
  const float* px_w2 = (const float*)d_in[17];
  const float* px_b2 = (const float*)d_in[18];
  const float* me_w1 = (const float*)d_in[19];
  const float* me_b1 = (const float*)d_in[20];
  const float* me_w2 = (const float*)d_in[21];
  const float* me_b2 = (const float*)d_in[22];
  const float* gih   = (const float*)d_in[23];
  const float* ghh   = (const float*)d_in[24];

  char* ws = (char*)d_ws;
  u16* wb    = (u16*)(ws + WS_WB);
  float* hst = (float*)(ws + WS_HST);
  float* prt = (float*)(ws + WS_PART);
  u16* uT    = (u16*)(ws + WS_UT);
  u16* yT    = (u16*)(ws + WS_YT);
  u16* phiu  = (u16*)(ws + WS_PHIU);
  u16* h1o   = (u16*)(ws + WS_H1);
  float* out = (float*)d_out;

  k_convert_weights<<<256, 256, 0, stream>>>(pu_w1, pu_w2, dy_w1, dy_w2, xm_w, xlv_w,
                                             px_w1, px_w2, me_w1, me_w2, gih, ghh,
                                             h0, wb, hst);
  for (int c = 0; c < NCH; ++c) {
    k_transpose<<<dim3(TC / 32, 256, 2), dim3(32, 8), 0, stream>>>(u, y, uT, yT, c * TC);
    k_phi_u<<<RC / 128, 256, 0, stream>>>(uT, wb, pu_b1, pu_b2, phiu);
    k_gru_seq<<<16, 512, 0, stream>>>(phiu, wb, hst, h1o);
    k_post<<<RC / 64, 128, 0, stream>>>(phiu, h1o, yT, wb, dy_b1, dy_b2, xm_b, xlv_b,
                                        px_b1, px_b2, me_b1, me_b2, prt, c == 0 ? 1 : 0);
  }
  k_finalize<<<1, 256, 0, stream>>>(prt, out);
}